// Round 8
// baseline (224.725 us; speedup 1.0000x reference)
//
#include <hip/hip_runtime.h>

typedef __bf16 bf16;
typedef __bf16 bf16x8 __attribute__((ext_vector_type(8)));
typedef __bf16 bf16x4 __attribute__((ext_vector_type(4)));
typedef float  f32x4  __attribute__((ext_vector_type(4)));
typedef unsigned u32x2 __attribute__((ext_vector_type(2)));

typedef __attribute__((address_space(1))) const void GASV;
typedef __attribute__((address_space(3))) void LASV;

__device__ __forceinline__ void gload16(const void* g, void* l) {
  __builtin_amdgcn_global_load_lds((GASV*)g, (LASV*)l, 16, 0, 0);
}

constexpr float CEXP = 0.125f * 1.44269504088896340736f;  // attn scale folded into exp2

// ---------------- weight transposes fp32->bf16 via LDS 32x32 tiles (both sides coalesced) --
__global__ __launch_bounds__(256) void wconv_all(const float* __restrict__ qkv_w,
                                                 const float* __restrict__ proj_w,
                                                 const float* __restrict__ w1,
                                                 const float* __restrict__ w2,
                                                 bf16* __restrict__ Wtqkv,
                                                 bf16* __restrict__ WtP,
                                                 bf16* __restrict__ Wt1,
                                                 bf16* __restrict__ Wt2) {
  __shared__ float td[32][33];
  const int t = blockIdx.x;   // 512 tiles
  const float* src;
  bf16* dst;
  int Kin, Nin, kt, nt;
  if (t < 192)      { src = qkv_w; dst = Wtqkv; Kin = 256; Nin = 768; kt = t & 7;          nt = t >> 3; }
  else if (t < 256) { src = proj_w; dst = WtP;  Kin = 256; Nin = 256; kt = (t - 192) & 7;  nt = (t - 192) >> 3; }
  else if (t < 384) { src = w1;    dst = Wt1;   Kin = 256; Nin = 512; kt = (t - 256) & 7;  nt = (t - 256) >> 3; }
  else              { src = w2;    dst = Wt2;   Kin = 512; Nin = 256; kt = (t - 384) & 15; nt = (t - 384) >> 4; }
  const int tid = threadIdx.x;
  {
    const int r = tid >> 3, c4 = (tid & 7) << 2;
    const float4 v = *(const float4*)(src + (size_t)(kt * 32 + r) * Nin + nt * 32 + c4);
    td[r][c4 + 0] = v.x; td[r][c4 + 1] = v.y; td[r][c4 + 2] = v.z; td[r][c4 + 3] = v.w;
  }
  __syncthreads();
  {
    const int n = tid >> 3, k4 = (tid & 7) << 2;
    bf16x4 o;
#pragma unroll
    for (int i = 0; i < 4; ++i) o[i] = (bf16)td[k4 + i][n];
    *(bf16x4*)(dst + (size_t)(nt * 32 + n) * Kin + kt * 32 + k4) = o;
  }
}

// ---------------- layernorm rows of 256 (fp32 in -> bf16 out); 1 wave per row ----------------
__global__ __launch_bounds__(256) void ln_fwd(const float* __restrict__ x,
                                              const float* __restrict__ gam,
                                              const float* __restrict__ bet,
                                              bf16* __restrict__ out) {
  const int lane = threadIdx.x & 63;
  const int w = threadIdx.x >> 6;
  const size_t row = (size_t)blockIdx.x * 4 + w;
  const float4 v = *(const float4*)(x + row * 256 + lane * 4);
  float s1 = v.x + v.y + v.z + v.w;
  float s2 = v.x * v.x + v.y * v.y + v.z * v.z + v.w * v.w;
#pragma unroll
  for (int m = 1; m < 64; m <<= 1) {
    s1 += __shfl_xor(s1, m);
    s2 += __shfl_xor(s2, m);
  }
  const float mu = s1 * (1.0f / 256.0f);
  const float var = s2 * (1.0f / 256.0f) - mu * mu;
  const float rs = rsqrtf(var + 1e-5f);
  const float4 g4 = *(const float4*)(gam + lane * 4);
  const float4 b4 = *(const float4*)(bet + lane * 4);
  bf16x4 o;
  o[0] = (bf16)((v.x - mu) * rs * g4.x + b4.x);
  o[1] = (bf16)((v.y - mu) * rs * g4.y + b4.y);
  o[2] = (bf16)((v.z - mu) * rs * g4.z + b4.z);
  o[3] = (bf16)((v.w - mu) * rs * g4.w + b4.w);
  *(bf16x4*)(out + row * 256 + lane * 4) = o;
}

// ---------------- BT-form GEMM, 128x128 tile, BK=64, FRAG-MAJOR LDS (unchanged r7) --------
template <int EPI>
__global__ __launch_bounds__(256) void gemm_bt(const bf16* __restrict__ A,
                                               const bf16* __restrict__ Bt,
                                               const float* __restrict__ bias,
                                               const float* __restrict__ res,
                                               void* __restrict__ outp,
                                               int M, int N, int K,
                                               const bf16* __restrict__ A2,
                                               const float* __restrict__ pstats) {
  constexpr bool MA = (EPI == 4);
  __shared__ bf16 Al[2][8192];
  __shared__ bf16 Bl[2][8192];
  const int tid = threadIdx.x;
  const int lane = tid & 63;
  const int W = tid >> 6;
  const int wm = W >> 1, wn = W & 1;
  const int qi = lane & 15, g = lane >> 4;
  const int nbm = M >> 7;
  const int bm = (int)blockIdx.x % nbm;
  const int bn = (int)blockIdx.x / nbm;
  const int m0 = bm << 7, n0 = bn << 7;
  const int nk = K >> 6;

  int rowg[4];
  const char* asrc[4];
  const char* bsrc[4];
#pragma unroll
  for (int p = 0; p < 4; ++p) {
    const int s = W * 4 + p;
    const int row = (s >> 3) * 64 + ((s >> 1) & 3) * 16 + qi;
    const int kb = (s & 1) * 64 + g * 16;
    rowg[p] = m0 + row;
    asrc[p] = (const char*)(A + (size_t)(m0 + row) * K) + kb;
    bsrc[p] = (const char*)(Bt + (size_t)(n0 + row) * K) + kb;
  }

  f32x4 acc[4][4];
#pragma unroll
  for (int i = 0; i < 4; ++i)
#pragma unroll
    for (int j = 0; j < 4; ++j) acc[i][j] = (f32x4){0.f, 0.f, 0.f, 0.f};

  bf16x8 pa0v[4], pa1v[4];
  float2 sst0[4], sst1[4];

  auto stagePlain = [&](int sl) {
#pragma unroll
    for (int p = 0; p < 4; ++p) {
      gload16(asrc[p], (char*)&Al[sl][0] + (W * 4 + p) * 1024);
      gload16(bsrc[p], (char*)&Bl[sl][0] + (W * 4 + p) * 1024);
      asrc[p] += 128;
      bsrc[p] += 128;
    }
  };
  auto stageMAload = [&](int sl, int t) {
#pragma unroll
    for (int p = 0; p < 4; ++p) {
      gload16(bsrc[p], (char*)&Bl[sl][0] + (W * 4 + p) * 1024);
      bsrc[p] += 128;
      pa0v[p] = *(const bf16x8*)(asrc[p]);
      pa1v[p] = *(const bf16x8*)((const char*)A2 + (asrc[p] - (const char*)A));
      asrc[p] += 128;
      const int bh = ((rowg[p] >> 11) << 2) + t;   // head == K-tile index for proj
      const int ql = rowg[p] & 2047;
      sst0[p] = *(const float2*)(pstats + ((size_t)bh * 2048 + ql) * 2);
      sst1[p] = *(const float2*)(pstats + ((size_t)(bh + 32) * 2048 + ql) * 2);
    }
  };
  auto stageMAwrite = [&](int sl) {
#pragma unroll
    for (int p = 0; p < 4; ++p) {
      const float mx = fmaxf(sst0[p].x, sst1[p].x);
      float a0 = exp2f(CEXP * (sst0[p].x - mx));
      float a1 = exp2f(CEXP * (sst1[p].x - mx));
      const float inv = 1.0f / (sst0[p].y * a0 + sst1[p].y * a1);
      a0 *= inv;
      a1 *= inv;
      bf16x8 wv;
#pragma unroll
      for (int j = 0; j < 8; ++j)
        wv[j] = (bf16)((float)pa0v[p][j] * a0 + (float)pa1v[p][j] * a1);
      *(bf16x8*)((char*)&Al[sl][0] + (W * 4 + p) * 1024 + lane * 16) = wv;
    }
  };

  if constexpr (MA) {
    stageMAload(0, 0);
    stageMAwrite(0);
  } else {
    stagePlain(0);
  }
  asm volatile("s_waitcnt vmcnt(0)" ::: "memory");
  if constexpr (MA) asm volatile("s_waitcnt lgkmcnt(0)" ::: "memory");
  __builtin_amdgcn_s_barrier();

  for (int t = 0; t < nk; ++t) {
    if (t + 1 < nk) {
      if constexpr (MA) stageMAload((t + 1) & 1, t + 1);
      else stagePlain((t + 1) & 1);
    }
    const char* pa = (const char*)&Al[t & 1][0] + wm * 8192 + lane * 16;
    const char* pb = (const char*)&Bl[t & 1][0] + wn * 8192 + lane * 16;
    bf16x8 av[4][2], bv[4][2];
#pragma unroll
    for (int f = 0; f < 4; ++f)
#pragma unroll
      for (int ks = 0; ks < 2; ++ks) {
        av[f][ks] = *(const bf16x8*)(pa + (f * 2 + ks) * 1024);
        bv[f][ks] = *(const bf16x8*)(pb + (f * 2 + ks) * 1024);
      }
    __builtin_amdgcn_s_setprio(1);
#pragma unroll
    for (int fm = 0; fm < 4; ++fm)
#pragma unroll
      for (int fn = 0; fn < 4; ++fn) {
        acc[fm][fn] = __builtin_amdgcn_mfma_f32_16x16x32_bf16(av[fm][0], bv[fn][0], acc[fm][fn], 0, 0, 0);
        acc[fm][fn] = __builtin_amdgcn_mfma_f32_16x16x32_bf16(av[fm][1], bv[fn][1], acc[fm][fn], 0, 0, 0);
      }
    __builtin_amdgcn_s_setprio(0);
    if (t + 1 < nk) {
      if constexpr (MA) stageMAwrite((t + 1) & 1);
    }
    asm volatile("s_waitcnt vmcnt(0)" ::: "memory");
    if constexpr (MA) asm volatile("s_waitcnt lgkmcnt(0)" ::: "memory");
    __builtin_amdgcn_s_barrier();
  }

#pragma unroll
  for (int fm = 0; fm < 4; ++fm)
#pragma unroll
    for (int fn = 0; fn < 4; ++fn) {
      const int r0 = m0 + wm * 64 + fm * 16 + ((lane >> 4) << 2);
      const int c = n0 + wn * 64 + fn * 16 + (lane & 15);
#pragma unroll
      for (int j = 0; j < 4; ++j) {
        const int r = r0 + j;
        const float v = acc[fm][fn][j];
        if constexpr (EPI == 0) {
          ((bf16*)outp)[(size_t)r * N + c] = (bf16)(v + bias[c]);
        } else if constexpr (EPI == 1) {
          ((bf16*)outp)[(size_t)r * 2048 + ((size_t)(c >> 11)) * 524288 + (c & 2047)] =
              (bf16)(v + bias[r]);
        } else if constexpr (EPI == 2 || EPI == 4) {
          ((float*)outp)[(size_t)r * N + c] = v + bias[c] + res[(size_t)r * N + c];
        } else {
          const float u = v + bias[c];
          ((bf16*)outp)[(size_t)r * N + c] = (bf16)(u * 0.5f * (1.0f + erff(u * 0.70710678118f)));
        }
      }
    }
}

// ---------------- flash attention v6: BARRIER-FREE, register-staged K/V --------------------
// 1024 blocks = 32 bh x 16 qt x 2 kv-halves; 4 independent waves/block (32 q each).
// K/V tiles double-buffered in VGPRs via plain global loads in MFMA-fragment layout;
// compiler emits counted vmcnt waits from register deps. Only per-wave-private P slab in LDS.
__global__ __launch_bounds__(256) void attn_fwd(const bf16* __restrict__ qk,
                                                const bf16* __restrict__ vT,
                                                bf16* __restrict__ po0,
                                                bf16* __restrict__ po1,
                                                float* __restrict__ pstats) {
  __shared__ bf16 Pl[4][1024];   // per-wave 2KB P slab
  const int tid = threadIdx.x;
  const int lane = tid & 63;
  const int w = tid >> 6;
  const int g = lane >> 4;
  const int qi = lane & 15;
  const int bid = (int)blockIdx.x;
  const int bh = bid & 31;          // same bh -> same XCD
  const int qt = (bid >> 5) & 15;
  const int s = bid >> 9;           // kv half
  const int b = bh >> 2, h = bh & 3;

  const size_t qrow0 = (size_t)b * 2048 + qt * 128 + w * 32 + qi;
  bf16x8 qf[2][2];
#pragma unroll
  for (int f = 0; f < 2; ++f) {
    const bf16* qp = qk + (qrow0 + f * 16) * 512 + h * 64 + g * 8;
    qf[f][0] = *(const bf16x8*)qp;
    qf[f][1] = *(const bf16x8*)(qp + 32);
  }

  float mrun[2] = {0.f, 0.f};
  float lsum[2] = {0.f, 0.f};
  f32x4 o[4][2];
#pragma unroll
  for (int i = 0; i < 4; ++i)
#pragma unroll
    for (int f = 0; f < 2; ++f) o[i][f] = (f32x4){0.f, 0.f, 0.f, 0.f};

  constexpr float THR = 8.0f / CEXP;

  // per-fragment global base pointers (MFMA layout: lane holds row fk*16+qi, bytes g*16(+64))
  const char* kbase = (const char*)qk + ((size_t)b * 2048) * 1024 + 512 + h * 128 +
                      (size_t)s * 16 * 65536;
  const char* vbase = (const char*)vT + (size_t)bh * 262144 + (size_t)s * 16 * 128;
  const char* kp[4];
  const char* vp[4];
#pragma unroll
  for (int fk = 0; fk < 4; ++fk) {
    kp[fk] = kbase + (fk * 16 + qi) * 1024 + g * 16;
    vp[fk] = vbase + (size_t)(fk * 16 + qi) * 4096 + g * 16;
  }

  char* const pw = (char*)&Pl[w][0];
  int paddrb[2];
#pragma unroll
  for (int bb = 0; bb < 2; ++bb)
    paddrb[bb] = (bb * 2 + (g >> 1)) * 256 + qi * 16 + (g & 1) * 8;
  const char* const prd = pw + lane * 16;

  bf16x8 kA[4][2], vA[4][2], kB[4][2], vB[4][2];

  auto LOAD = [&](bf16x8 (&kr)[4][2], bf16x8 (&vr)[4][2]) {
#pragma unroll
    for (int fk = 0; fk < 4; ++fk) {
      kr[fk][0] = *(const bf16x8*)(kp[fk]);
      kr[fk][1] = *(const bf16x8*)(kp[fk] + 64);
      vr[fk][0] = *(const bf16x8*)(vp[fk]);
      vr[fk][1] = *(const bf16x8*)(vp[fk] + 64);
      kp[fk] += 65536;   // next kv tile (64 rows x 1KB)
      vp[fk] += 128;     // next kv tile (64 cols x 2B)
    }
  };

  auto COMPUTE = [&](bf16x8 (&kr)[4][2], bf16x8 (&vr)[4][2]) {
    // ---- S^T = K·Q^T straight from registers ----
    f32x4 st[4][2];
    __builtin_amdgcn_s_setprio(1);
#pragma unroll
    for (int fk = 0; fk < 4; ++fk)
#pragma unroll
      for (int f = 0; f < 2; ++f) {
        f32x4 z = (f32x4){0.f, 0.f, 0.f, 0.f};
        st[fk][f] = __builtin_amdgcn_mfma_f32_16x16x32_bf16(kr[fk][0], qf[f][0], z, 0, 0, 0);
        st[fk][f] = __builtin_amdgcn_mfma_f32_16x16x32_bf16(kr[fk][1], qf[f][1], st[fk][f], 0, 0, 0);
      }
    __builtin_amdgcn_s_setprio(0);
    // ---- online softmax (lane-local col q; kv slice = fk*16+g*4+j) ----
    float pmax[2];
#pragma unroll
    for (int f = 0; f < 2; ++f) {
      float m0 = fmaxf(fmaxf(st[0][f][0], st[0][f][1]), fmaxf(st[0][f][2], st[0][f][3]));
      float m1 = fmaxf(fmaxf(st[1][f][0], st[1][f][1]), fmaxf(st[1][f][2], st[1][f][3]));
      float m2 = fmaxf(fmaxf(st[2][f][0], st[2][f][1]), fmaxf(st[2][f][2], st[2][f][3]));
      float m3 = fmaxf(fmaxf(st[3][f][0], st[3][f][1]), fmaxf(st[3][f][2], st[3][f][3]));
      pmax[f] = fmaxf(fmaxf(m0, m1), fmaxf(m2, m3));
    }
    if (!__all(pmax[0] <= mrun[0] + THR && pmax[1] <= mrun[1] + THR)) {   // rare
#pragma unroll
      for (int f = 0; f < 2; ++f) {
        float mt = fmaxf(pmax[f], __shfl_xor(pmax[f], 16));
        mt = fmaxf(mt, __shfl_xor(mt, 32));
        const float mnew = fmaxf(mrun[f], mt);
        const float alpha = exp2f(CEXP * (mrun[f] - mnew));
        lsum[f] *= alpha;
#pragma unroll
        for (int fd = 0; fd < 4; ++fd)
#pragma unroll
          for (int j = 0; j < 4; ++j) o[fd][f][j] *= alpha;
        mrun[f] = mnew;
      }
    }
    unsigned pk[4][2][2];
#pragma unroll
    for (int f = 0; f < 2; ++f) {
      const float negcm = -CEXP * mrun[f];
      float ts = 0.f;
#pragma unroll
      for (int fk = 0; fk < 4; ++fk)
#pragma unroll
        for (int jp = 0; jp < 2; ++jp) {
          const float p0 = exp2f(fmaf(st[fk][f][2 * jp], CEXP, negcm));
          const float p1 = exp2f(fmaf(st[fk][f][2 * jp + 1], CEXP, negcm));
          ts += p0 + p1;
          union { bf16 h2[2]; unsigned u; } cv;
          cv.h2[0] = (bf16)p0;
          cv.h2[1] = (bf16)p1;
          pk[fk][f][jp] = cv.u;
        }
      lsum[f] += ts;
    }
    // ---- PV per ksl-half: per-wave P slab round-trip (lgkm only, no barrier) ----
#pragma unroll
    for (int ksl = 0; ksl < 2; ++ksl) {
#pragma unroll
      for (int bb = 0; bb < 2; ++bb) {
        const int fk = 2 * ksl + bb;
#pragma unroll
        for (int f = 0; f < 2; ++f) {
          u32x2 pv2;
          pv2[0] = pk[fk][f][0];
          pv2[1] = pk[fk][f][1];
          *(u32x2*)(pw + f * 1024 + paddrb[bb]) = pv2;
        }
      }
      bf16x8 pa[2];
#pragma unroll
      for (int f = 0; f < 2; ++f) pa[f] = *(const bf16x8*)(prd + f * 1024);
      __builtin_amdgcn_s_setprio(1);
#pragma unroll
      for (int fd = 0; fd < 4; ++fd)
#pragma unroll
        for (int f = 0; f < 2; ++f)
          o[fd][f] = __builtin_amdgcn_mfma_f32_16x16x32_bf16(vr[fd][ksl], pa[f], o[fd][f], 0, 0, 0);
      __builtin_amdgcn_s_setprio(0);
    }
  };

  LOAD(kA, vA);   // tile 0
#pragma unroll 1
  for (int tt = 0; tt < 8; ++tt) {
    LOAD(kB, vB);                    // tile 2tt+1 in flight during compute(A)
    COMPUTE(kA, vA);
    if (tt < 7) LOAD(kA, vA);        // tile 2tt+2 in flight during compute(B)
    COMPUTE(kB, vB);
  }

  // ---- epilogue: reduce lsum across g-groups, write stats + unnormalized bf16 partials ----
#pragma unroll
  for (int f = 0; f < 2; ++f) {
    float l = lsum[f];
    l += __shfl_xor(l, 16);
    l += __shfl_xor(l, 32);
    lsum[f] = l;
  }
  if (g == 0) {
#pragma unroll
    for (int f = 0; f < 2; ++f) {
      float2 sv;
      sv.x = mrun[f];
      sv.y = lsum[f];
      *(float2*)(pstats + (((size_t)s * 32 + bh) * 2048 + qt * 128 + w * 32 + f * 16 + qi) * 2) = sv;
    }
  }
  bf16* const pob = s ? po1 : po0;
#pragma unroll
  for (int f = 0; f < 2; ++f) {
    bf16* const orow = pob + (qrow0 + f * 16) * 256 + h * 64 + g * 4;
#pragma unroll
    for (int fd = 0; fd < 4; ++fd) {
      bf16x4 ov;
#pragma unroll
      for (int j = 0; j < 4; ++j) ov[j] = (bf16)o[fd][f][j];
      *(bf16x4*)(orow + fd * 16) = ov;
    }
  }
}

extern "C" void kernel_launch(void* const* d_in, const int* in_sizes, int n_in,
                              void* d_out, int out_size, void* d_ws, size_t ws_size,
                              hipStream_t stream) {
  const float* x      = (const float*)d_in[0];
  const float* qkv_w  = (const float*)d_in[1];
  const float* qkv_b  = (const float*)d_in[2];
  const float* proj_w = (const float*)d_in[3];
  const float* proj_b = (const float*)d_in[4];
  const float* ln1_g  = (const float*)d_in[5];
  const float* ln1_b  = (const float*)d_in[6];
  const float* ln2_g  = (const float*)d_in[7];
  const float* ln2_b  = (const float*)d_in[8];
  const float* mlp_w1 = (const float*)d_in[9];
  const float* mlp_b1 = (const float*)d_in[10];
  const float* mlp_w2 = (const float*)d_in[11];
  const float* mlp_b2 = (const float*)d_in[12];
  float* out = (float*)d_out;

  char* ws = (char*)d_ws;
  bf16* Wtqkv = (bf16*)(ws);              // [768][256]   393216 B
  bf16* WtP   = (bf16*)(ws + 393216);     // [256][256]   131072 B
  bf16* Wt1   = (bf16*)(ws + 524288);     // [512][256]   262144 B
  bf16* Wt2   = (bf16*)(ws + 786432);     // [256][512]   262144 B
  bf16* h     = (bf16*)(ws + 1048576);    // [16384][256] 8388608 B  (ln1 out; dead after V gemm)
  bf16* qkb   = (bf16*)(ws + 9437184);    // [16384][512] 16777216 B
  bf16* vT    = (bf16*)(ws + 26214400);   // [32][64][2048] 8388608 B
  bf16* po1   = (bf16*)(ws + 34603008);   // [16384][256] 8388608 B  (kv-half-1 partial)
  float* x2   = (float*)(ws + 42991616);  // [16384][256] 16777216 B
  float* pstats = (float*)(ws + 59768832);// [2][32][2048][2] f32  1 MB  (total 60.8 MB)
  bf16* po0 = h;   // kv-half-0 partial reuses h region (h dead once attn starts)
  bf16* a1 = qkb;  // fc1 out reuses qkb (dead after attn)
  bf16* h2 = h;    // ln2 out reuses h region (po0 dead after proj)

  wconv_all<<<512, 256, 0, stream>>>(qkv_w, proj_w, mlp_w1, mlp_w2, Wtqkv, WtP, Wt1, Wt2);

  ln_fwd<<<4096, 256, 0, stream>>>(x, ln1_g, ln1_b, h);
  // Q,K: h @ W_qk  -> qkb [16384][512]
  gemm_bt<0><<<512, 256, 0, stream>>>(h, Wtqkv, qkv_b, nullptr, qkb, 16384, 512, 256, nullptr, nullptr);
  // V^T: Wv^T @ h^T -> vT [32][64][2048]  (swapped-operand GEMM, scatter epilogue)
  gemm_bt<1><<<256, 256, 0, stream>>>(Wtqkv + 512 * 256, h, qkv_b + 512, nullptr, vT, 256, 16384, 256, nullptr, nullptr);
  attn_fwd<<<1024, 256, 0, stream>>>(qkb, vT, po0, po1, pstats);
  // proj + residual -> x2 (f32), flash-merge of (po0,po1) fused into A staging
  gemm_bt<4><<<256, 256, 0, stream>>>(po0, WtP, proj_b, x, x2, 16384, 256, 256, po1, pstats);
  ln_fwd<<<4096, 256, 0, stream>>>(x2, ln2_g, ln2_b, h2);
  // fc1 + gelu -> a1 (bf16)
  gemm_bt<3><<<512, 256, 0, stream>>>(h2, Wt1, mlp_b1, nullptr, a1, 16384, 512, 256, nullptr, nullptr);
  // fc2 + residual -> out (f32)
  gemm_bt<2><<<256, 256, 0, stream>>>(a1, Wt2, mlp_b2, x2, out, 16384, 256, 512, nullptr, nullptr);
}

// Round 9
// 170.715 us; speedup vs baseline: 1.3164x; 1.3164x over previous
//
#include <hip/hip_runtime.h>

typedef __bf16 bf16;
typedef __bf16 bf16x8 __attribute__((ext_vector_type(8)));
typedef __bf16 bf16x4 __attribute__((ext_vector_type(4)));
typedef float  f32x4  __attribute__((ext_vector_type(4)));
typedef unsigned u32x2 __attribute__((ext_vector_type(2)));

typedef __attribute__((address_space(1))) const void GASV;
typedef __attribute__((address_space(3))) void LASV;

__device__ __forceinline__ void gload16(const void* g, void* l) {
  __builtin_amdgcn_global_load_lds((GASV*)g, (LASV*)l, 16, 0, 0);
}

constexpr float CEXP = 0.125f * 1.44269504088896340736f;  // attn scale folded into exp2

// ---------------- fused: weight transposes (blocks 0-511) + layernorm1 (blocks 512-4607) ----
__global__ __launch_bounds__(256) void prep_fused(const float* __restrict__ qkv_w,
                                                  const float* __restrict__ proj_w,
                                                  const float* __restrict__ w1,
                                                  const float* __restrict__ w2,
                                                  bf16* __restrict__ Wtqkv,
                                                  bf16* __restrict__ WtP,
                                                  bf16* __restrict__ Wt1,
                                                  bf16* __restrict__ Wt2,
                                                  const float* __restrict__ x,
                                                  const float* __restrict__ gam,
                                                  const float* __restrict__ bet,
                                                  bf16* __restrict__ hout) {
  __shared__ float td[32][33];
  const int blk = blockIdx.x;
  const int tid = threadIdx.x;
  if (blk >= 512) {   // ---- layernorm path ----
    const int lane = tid & 63;
    const int w = tid >> 6;
    const size_t row = (size_t)(blk - 512) * 4 + w;
    const float4 v = *(const float4*)(x + row * 256 + lane * 4);
    float s1 = v.x + v.y + v.z + v.w;
    float s2 = v.x * v.x + v.y * v.y + v.z * v.z + v.w * v.w;
#pragma unroll
    for (int m = 1; m < 64; m <<= 1) {
      s1 += __shfl_xor(s1, m);
      s2 += __shfl_xor(s2, m);
    }
    const float mu = s1 * (1.0f / 256.0f);
    const float var = s2 * (1.0f / 256.0f) - mu * mu;
    const float rs = rsqrtf(var + 1e-5f);
    const float4 g4 = *(const float4*)(gam + lane * 4);
    const float4 b4 = *(const float4*)(bet + lane * 4);
    bf16x4 o;
    o[0] = (bf16)((v.x - mu) * rs * g4.x + b4.x);
    o[1] = (bf16)((v.y - mu) * rs * g4.y + b4.y);
    o[2] = (bf16)((v.z - mu) * rs * g4.z + b4.z);
    o[3] = (bf16)((v.w - mu) * rs * g4.w + b4.w);
    *(bf16x4*)(hout + row * 256 + lane * 4) = o;
    return;
  }
  // ---- weight transpose path ----
  const int t = blk;
  const float* src;
  bf16* dst;
  int Kin, Nin, kt, nt;
  if (t < 192)      { src = qkv_w; dst = Wtqkv; Kin = 256; Nin = 768; kt = t & 7;          nt = t >> 3; }
  else if (t < 256) { src = proj_w; dst = WtP;  Kin = 256; Nin = 256; kt = (t - 192) & 7;  nt = (t - 192) >> 3; }
  else if (t < 384) { src = w1;    dst = Wt1;   Kin = 256; Nin = 512; kt = (t - 256) & 7;  nt = (t - 256) >> 3; }
  else              { src = w2;    dst = Wt2;   Kin = 512; Nin = 256; kt = (t - 384) & 15; nt = (t - 384) >> 4; }
  {
    const int r = tid >> 3, c4 = (tid & 7) << 2;
    const float4 v = *(const float4*)(src + (size_t)(kt * 32 + r) * Nin + nt * 32 + c4);
    td[r][c4 + 0] = v.x; td[r][c4 + 1] = v.y; td[r][c4 + 2] = v.z; td[r][c4 + 3] = v.w;
  }
  __syncthreads();
  {
    const int n = tid >> 3, k4 = (tid & 7) << 2;
    bf16x4 o;
#pragma unroll
    for (int i = 0; i < 4; ++i) o[i] = (bf16)td[k4 + i][n];
    *(bf16x4*)(dst + (size_t)(nt * 32 + n) * Kin + kt * 32 + k4) = o;
  }
}

// ---------------- layernorm rows of 256 (fp32 in -> bf16 out); 1 wave per row ----------------
__global__ __launch_bounds__(256) void ln_fwd(const float* __restrict__ x,
                                              const float* __restrict__ gam,
                                              const float* __restrict__ bet,
                                              bf16* __restrict__ out) {
  const int lane = threadIdx.x & 63;
  const int w = threadIdx.x >> 6;
  const size_t row = (size_t)blockIdx.x * 4 + w;
  const float4 v = *(const float4*)(x + row * 256 + lane * 4);
  float s1 = v.x + v.y + v.z + v.w;
  float s2 = v.x * v.x + v.y * v.y + v.z * v.z + v.w * v.w;
#pragma unroll
  for (int m = 1; m < 64; m <<= 1) {
    s1 += __shfl_xor(s1, m);
    s2 += __shfl_xor(s2, m);
  }
  const float mu = s1 * (1.0f / 256.0f);
  const float var = s2 * (1.0f / 256.0f) - mu * mu;
  const float rs = rsqrtf(var + 1e-5f);
  const float4 g4 = *(const float4*)(gam + lane * 4);
  const float4 b4 = *(const float4*)(bet + lane * 4);
  bf16x4 o;
  o[0] = (bf16)((v.x - mu) * rs * g4.x + b4.x);
  o[1] = (bf16)((v.y - mu) * rs * g4.y + b4.y);
  o[2] = (bf16)((v.z - mu) * rs * g4.z + b4.z);
  o[3] = (bf16)((v.w - mu) * rs * g4.w + b4.w);
  *(bf16x4*)(out + row * 256 + lane * 4) = o;
}

// ---------------- BT-form GEMM, 128x128 tile, BK=64, 512 threads (8 waves 2x4) -------------
// Frag-major LDS: slot s holds rows (s>>3)*64+((s>>1)&3)*16+qi, k-half (s&1); all K-loop
// ds_reads are base + lane*16 + imm. 8 waves -> 16 waves/CU at 2 blocks/CU (double r7 TLP).
template <int EPI>
__global__ __launch_bounds__(512) void gemm_bt(const bf16* __restrict__ A,
                                               const bf16* __restrict__ Bt,
                                               const float* __restrict__ bias,
                                               const float* __restrict__ res,
                                               void* __restrict__ outp,
                                               int M, int N, int K) {
  __shared__ bf16 Al[2][8192];
  __shared__ bf16 Bl[2][8192];
  const int tid = threadIdx.x;
  const int lane = tid & 63;
  const int W = tid >> 6;          // 0..7
  const int wm = W >> 2, wn = W & 3;
  const int qi = lane & 15, g = lane >> 4;
  const int nbm = M >> 7;
  const int bm = (int)blockIdx.x % nbm;
  const int bn = (int)blockIdx.x / nbm;
  const int m0 = bm << 7, n0 = bn << 7;
  const int nk = K >> 6;

  const char* asrc[2];
  const char* bsrc[2];
#pragma unroll
  for (int p = 0; p < 2; ++p) {
    const int s = p * 8 + W;
    const int row = (s >> 3) * 64 + ((s >> 1) & 3) * 16 + qi;
    const int kb = (s & 1) * 64 + g * 16;
    asrc[p] = (const char*)(A + (size_t)(m0 + row) * K) + kb;
    bsrc[p] = (const char*)(Bt + (size_t)(n0 + row) * K) + kb;
  }

  f32x4 acc[4][2];
#pragma unroll
  for (int i = 0; i < 4; ++i)
#pragma unroll
    for (int j = 0; j < 2; ++j) acc[i][j] = (f32x4){0.f, 0.f, 0.f, 0.f};

  auto stage = [&](int sl) {
#pragma unroll
    for (int p = 0; p < 2; ++p) {
      gload16(asrc[p], (char*)&Al[sl][0] + (p * 8 + W) * 1024);
      gload16(bsrc[p], (char*)&Bl[sl][0] + (p * 8 + W) * 1024);
      asrc[p] += 128;
      bsrc[p] += 128;
    }
  };

  stage(0);
  asm volatile("s_waitcnt vmcnt(0)" ::: "memory");
  __builtin_amdgcn_s_barrier();

  for (int t = 0; t < nk; ++t) {
    if (t + 1 < nk) stage((t + 1) & 1);
    const char* pa = (const char*)&Al[t & 1][0] + wm * 8192 + lane * 16;
    const char* pb = (const char*)&Bl[t & 1][0] + lane * 16;
    bf16x8 av[4][2], bv[2][2];
#pragma unroll
    for (int f = 0; f < 4; ++f)
#pragma unroll
      for (int ks = 0; ks < 2; ++ks)
        av[f][ks] = *(const bf16x8*)(pa + (f * 2 + ks) * 1024);
#pragma unroll
    for (int fn = 0; fn < 2; ++fn)
#pragma unroll
      for (int ks = 0; ks < 2; ++ks) {
        const int r16 = wn * 2 + fn;
        bv[fn][ks] = *(const bf16x8*)(pb + ((r16 >> 2) * 8 + (r16 & 3) * 2 + ks) * 1024);
      }
    __builtin_amdgcn_s_setprio(1);
#pragma unroll
    for (int fm = 0; fm < 4; ++fm)
#pragma unroll
      for (int fn = 0; fn < 2; ++fn) {
        acc[fm][fn] = __builtin_amdgcn_mfma_f32_16x16x32_bf16(av[fm][0], bv[fn][0], acc[fm][fn], 0, 0, 0);
        acc[fm][fn] = __builtin_amdgcn_mfma_f32_16x16x32_bf16(av[fm][1], bv[fn][1], acc[fm][fn], 0, 0, 0);
      }
    __builtin_amdgcn_s_setprio(0);
    asm volatile("s_waitcnt vmcnt(0)" ::: "memory");
    __builtin_amdgcn_s_barrier();
  }

#pragma unroll
  for (int fm = 0; fm < 4; ++fm)
#pragma unroll
    for (int fn = 0; fn < 2; ++fn) {
      const int r0 = m0 + wm * 64 + fm * 16 + g * 4;
      const int c = n0 + wn * 32 + fn * 16 + qi;
#pragma unroll
      for (int j = 0; j < 4; ++j) {
        const int r = r0 + j;
        const float v = acc[fm][fn][j];
        if constexpr (EPI == 0) {
          ((bf16*)outp)[(size_t)r * N + c] = (bf16)(v + bias[c]);
        } else if constexpr (EPI == 1) {
          ((bf16*)outp)[(size_t)r * 2048 + ((size_t)(c >> 11)) * 524288 + (c & 2047)] =
              (bf16)(v + bias[r]);
        } else if constexpr (EPI == 2) {
          ((float*)outp)[(size_t)r * N + c] = v + bias[c] + res[(size_t)r * N + c];
        } else {
          const float u = v + bias[c];
          ((bf16*)outp)[(size_t)r * N + c] = (bf16)(u * 0.5f * (1.0f + erff(u * 0.70710678118f)));
        }
      }
    }
}

// ---------------- flash attention v5 (frozen: r7 version, 92 us) ---------------------------
__global__ __launch_bounds__(256) void attn_fwd(const bf16* __restrict__ qk,
                                                const bf16* __restrict__ vT,
                                                bf16* __restrict__ po0,
                                                bf16* __restrict__ po1,
                                                float* __restrict__ pstats) {
  __shared__ bf16 Kl[2][4096];
  __shared__ bf16 Vl[2][4096];
  __shared__ bf16 Pl[4][1024];
  const int tid = threadIdx.x;
  const int lane = tid & 63;
  const int w = tid >> 6;
  const int g = lane >> 4;
  const int qi = lane & 15;
  const int bid = (int)blockIdx.x;
  const int bh = bid & 31;
  const int qt = (bid >> 5) & 15;
  const int s = bid >> 9;
  const int b = bh >> 2, h = bh & 3;

  const size_t qrow0 = (size_t)b * 2048 + qt * 128 + w * 32 + qi;
  bf16x8 qf[2][2];
#pragma unroll
  for (int f = 0; f < 2; ++f) {
    const bf16* qp = qk + (qrow0 + f * 16) * 512 + h * 64 + g * 8;
    qf[f][0] = *(const bf16x8*)qp;
    qf[f][1] = *(const bf16x8*)(qp + 32);
  }

  float mrun[2] = {0.f, 0.f};
  float lsum[2] = {0.f, 0.f};
  f32x4 o[4][2];
#pragma unroll
  for (int i = 0; i < 4; ++i)
#pragma unroll
    for (int f = 0; f < 2; ++f) o[i][f] = (f32x4){0.f, 0.f, 0.f, 0.f};

  constexpr float THR = 8.0f / CEXP;

  const char* kbase = (const char*)qk + ((size_t)b * 2048) * 1024 + 512 + h * 128 +
                      (size_t)s * 16 * 65536;
  const char* vbase = (const char*)vT + (size_t)bh * 262144 + (size_t)s * 16 * 128;
  const char* ks[2];
  const char* vs[2];
#pragma unroll
  for (int i = 0; i < 2; ++i) {
    const int fk = i * 2 + (w >> 1);
    const int half = w & 1;
    ks[i] = kbase + (fk * 16 + qi) * 1024 + half * 64 + g * 16;
    vs[i] = vbase + (size_t)(fk * 16 + qi) * 4096 + half * 64 + g * 16;
  }
  char* const pw = (char*)&Pl[w][0];
  int paddrb[2];
#pragma unroll
  for (int bb = 0; bb < 2; ++bb)
    paddrb[bb] = (bb * 2 + (g >> 1)) * 256 + qi * 16 + (g & 1) * 8;
  const char* const prd = pw + lane * 16;

  auto stage = [&](int slot) {
    char* kd = (char*)&Kl[0][0] + slot * 8192 + w * 1024;
    char* vd = (char*)&Vl[0][0] + slot * 8192 + w * 1024;
    gload16(ks[0], kd);
    gload16(ks[1], kd + 4096);
    gload16(vs[0], vd);
    gload16(vs[1], vd + 4096);
    ks[0] += 65536; ks[1] += 65536;
    vs[0] += 128;   vs[1] += 128;
  };

  stage(0);
  asm volatile("s_waitcnt vmcnt(0)" ::: "memory");
  __builtin_amdgcn_s_barrier();

  for (int t = 0; t < 16; ++t) {
    if (t < 15) stage((t + 1) & 1);
    const char* kb = (const char*)&Kl[0][0] + (t & 1) * 8192 + lane * 16;
    f32x4 st[4][2];
    __builtin_amdgcn_s_setprio(1);
#pragma unroll
    for (int fk = 0; fk < 4; ++fk) {
      const bf16x8 k0 = *(const bf16x8*)(kb + fk * 2048);
      const bf16x8 k1 = *(const bf16x8*)(kb + fk * 2048 + 1024);
#pragma unroll
      for (int f = 0; f < 2; ++f) {
        f32x4 z = (f32x4){0.f, 0.f, 0.f, 0.f};
        st[fk][f] = __builtin_amdgcn_mfma_f32_16x16x32_bf16(k0, qf[f][0], z, 0, 0, 0);
        st[fk][f] = __builtin_amdgcn_mfma_f32_16x16x32_bf16(k1, qf[f][1], st[fk][f], 0, 0, 0);
      }
    }
    __builtin_amdgcn_s_setprio(0);
    float pmax[2];
#pragma unroll
    for (int f = 0; f < 2; ++f) {
      float m0 = fmaxf(fmaxf(st[0][f][0], st[0][f][1]), fmaxf(st[0][f][2], st[0][f][3]));
      float m1 = fmaxf(fmaxf(st[1][f][0], st[1][f][1]), fmaxf(st[1][f][2], st[1][f][3]));
      float m2 = fmaxf(fmaxf(st[2][f][0], st[2][f][1]), fmaxf(st[2][f][2], st[2][f][3]));
      float m3 = fmaxf(fmaxf(st[3][f][0], st[3][f][1]), fmaxf(st[3][f][2], st[3][f][3]));
      pmax[f] = fmaxf(fmaxf(m0, m1), fmaxf(m2, m3));
    }
    if (!__all(pmax[0] <= mrun[0] + THR && pmax[1] <= mrun[1] + THR)) {
#pragma unroll
      for (int f = 0; f < 2; ++f) {
        float mt = fmaxf(pmax[f], __shfl_xor(pmax[f], 16));
        mt = fmaxf(mt, __shfl_xor(mt, 32));
        const float mnew = fmaxf(mrun[f], mt);
        const float alpha = exp2f(CEXP * (mrun[f] - mnew));
        lsum[f] *= alpha;
#pragma unroll
        for (int fd = 0; fd < 4; ++fd)
#pragma unroll
          for (int j = 0; j < 4; ++j) o[fd][f][j] *= alpha;
        mrun[f] = mnew;
      }
    }
    unsigned pk[4][2][2];
#pragma unroll
    for (int f = 0; f < 2; ++f) {
      const float negcm = -CEXP * mrun[f];
      float ts = 0.f;
#pragma unroll
      for (int fk = 0; fk < 4; ++fk)
#pragma unroll
        for (int jp = 0; jp < 2; ++jp) {
          const float p0 = exp2f(fmaf(st[fk][f][2 * jp], CEXP, negcm));
          const float p1 = exp2f(fmaf(st[fk][f][2 * jp + 1], CEXP, negcm));
          ts += p0 + p1;
          union { bf16 h2[2]; unsigned u; } cv;
          cv.h2[0] = (bf16)p0;
          cv.h2[1] = (bf16)p1;
          pk[fk][f][jp] = cv.u;
        }
      lsum[f] += ts;
    }
    const char* vb = (const char*)&Vl[0][0] + (t & 1) * 8192 + lane * 16;
#pragma unroll
    for (int ksl = 0; ksl < 2; ++ksl) {
#pragma unroll
      for (int bb = 0; bb < 2; ++bb) {
        const int fk = 2 * ksl + bb;
#pragma unroll
        for (int f = 0; f < 2; ++f) {
          u32x2 pv2;
          pv2[0] = pk[fk][f][0];
          pv2[1] = pk[fk][f][1];
          *(u32x2*)(pw + f * 1024 + paddrb[bb]) = pv2;
        }
      }
      bf16x8 pa[2];
#pragma unroll
      for (int f = 0; f < 2; ++f) pa[f] = *(const bf16x8*)(prd + f * 1024);
      __builtin_amdgcn_s_setprio(1);
#pragma unroll
      for (int fd = 0; fd < 4; ++fd) {
        const bf16x8 vv = *(const bf16x8*)(vb + fd * 2048 + ksl * 1024);
#pragma unroll
        for (int f = 0; f < 2; ++f)
          o[fd][f] = __builtin_amdgcn_mfma_f32_16x16x32_bf16(vv, pa[f], o[fd][f], 0, 0, 0);
      }
      __builtin_amdgcn_s_setprio(0);
    }
    asm volatile("s_waitcnt vmcnt(0)" ::: "memory");
    __builtin_amdgcn_s_barrier();
  }

#pragma unroll
  for (int f = 0; f < 2; ++f) {
    float l = lsum[f];
    l += __shfl_xor(l, 16);
    l += __shfl_xor(l, 32);
    lsum[f] = l;
  }
  if (g == 0) {
#pragma unroll
    for (int f = 0; f < 2; ++f) {
      float2 sv;
      sv.x = mrun[f];
      sv.y = lsum[f];
      *(float2*)(pstats + (((size_t)s * 32 + bh) * 2048 + qt * 128 + w * 32 + f * 16 + qi) * 2) = sv;
    }
  }
  bf16* const pob = s ? po1 : po0;
#pragma unroll
  for (int f = 0; f < 2; ++f) {
    bf16* const orow = pob + (qrow0 + f * 16) * 256 + h * 64 + g * 4;
#pragma unroll
    for (int fd = 0; fd < 4; ++fd) {
      bf16x4 ov;
#pragma unroll
      for (int j = 0; j < 4; ++j) ov[j] = (bf16)o[fd][f][j];
      *(bf16x4*)(orow + fd * 16) = ov;
    }
  }
}

// ---------------- flash merge of the two kv-half partials ----------------------------------
__global__ __launch_bounds__(256) void attn_merge(const bf16* __restrict__ po0,
                                                  const bf16* __restrict__ po1,
                                                  const float* __restrict__ pstats,
                                                  bf16* __restrict__ ob) {
  const int idx = blockIdx.x * 256 + threadIdx.x;   // 16384*64
  const int r = idx >> 6;
  const int cq = (idx & 63) * 4;
  const int h = cq >> 6;
  const int bh = (r >> 11) * 4 + h;
  const int ql = r & 2047;
  const float2 s0 = *(const float2*)(pstats + (((size_t)bh) * 2048 + ql) * 2);
  const float2 s1 = *(const float2*)(pstats + (((size_t)32 + bh) * 2048 + ql) * 2);
  const float M = fmaxf(s0.x, s1.x);
  const float a0 = exp2f(CEXP * (s0.x - M));
  const float a1 = exp2f(CEXP * (s1.x - M));
  const float inv = 1.0f / (s0.y * a0 + s1.y * a1);
  const bf16x4 p0 = *(const bf16x4*)(po0 + (size_t)r * 256 + cq);
  const bf16x4 p1 = *(const bf16x4*)(po1 + (size_t)r * 256 + cq);
  bf16x4 ov;
#pragma unroll
  for (int j = 0; j < 4; ++j)
    ov[j] = (bf16)(((float)p0[j] * a0 + (float)p1[j] * a1) * inv);
  *(bf16x4*)(ob + (size_t)r * 256 + cq) = ov;
}

extern "C" void kernel_launch(void* const* d_in, const int* in_sizes, int n_in,
                              void* d_out, int out_size, void* d_ws, size_t ws_size,
                              hipStream_t stream) {
  const float* x      = (const float*)d_in[0];
  const float* qkv_w  = (const float*)d_in[1];
  const float* qkv_b  = (const float*)d_in[2];
  const float* proj_w = (const float*)d_in[3];
  const float* proj_b = (const float*)d_in[4];
  const float* ln1_g  = (const float*)d_in[5];
  const float* ln1_b  = (const float*)d_in[6];
  const float* ln2_g  = (const float*)d_in[7];
  const float* ln2_b  = (const float*)d_in[8];
  const float* mlp_w1 = (const float*)d_in[9];
  const float* mlp_b1 = (const float*)d_in[10];
  const float* mlp_w2 = (const float*)d_in[11];
  const float* mlp_b2 = (const float*)d_in[12];
  float* out = (float*)d_out;

  char* ws = (char*)d_ws;
  bf16* Wtqkv = (bf16*)(ws);              // [768][256]   393216 B
  bf16* WtP   = (bf16*)(ws + 393216);     // [256][256]   131072 B
  bf16* Wt1   = (bf16*)(ws + 524288);     // [512][256]   262144 B
  bf16* Wt2   = (bf16*)(ws + 786432);     // [256][512]   262144 B
  bf16* h     = (bf16*)(ws + 1048576);    // [16384][256] 8388608 B  (ln1 out; dead after V gemm)
  bf16* qkb   = (bf16*)(ws + 9437184);    // [16384][512] 16777216 B
  bf16* vT    = (bf16*)(ws + 26214400);   // [32][64][2048] 8388608 B (dead after attn -> obuf)
  bf16* po1   = (bf16*)(ws + 34603008);   // [16384][256] 8388608 B  (kv-half-1 partial)
  float* x2   = (float*)(ws + 42991616);  // [16384][256] 16777216 B
  float* pstats = (float*)(ws + 59768832);// [2][32][2048][2] f32  1 MB  (total 60.8 MB)
  bf16* po0  = h;            // kv-half-0 partial reuses h (dead once attn starts)
  bf16* obuf = vT;           // merged attn output reuses vT (dead after attn)
  bf16* a1 = qkb;            // fc1 out reuses qkb (dead after attn)
  bf16* h2 = h;              // ln2 out reuses h region (po0 dead after merge)

  // wconv (512 blocks) + ln1 (4096 blocks) fused
  prep_fused<<<4608, 256, 0, stream>>>(qkv_w, proj_w, mlp_w1, mlp_w2, Wtqkv, WtP, Wt1, Wt2,
                                       x, ln1_g, ln1_b, h);
  // Q,K: h @ W_qk  -> qkb [16384][512]
  gemm_bt<0><<<512, 512, 0, stream>>>(h, Wtqkv, qkv_b, nullptr, qkb, 16384, 512, 256);
  // V^T: Wv^T @ h^T -> vT [32][64][2048]  (swapped-operand GEMM, scatter epilogue)
  gemm_bt<1><<<256, 512, 0, stream>>>(Wtqkv + 512 * 256, h, qkv_b + 512, nullptr, vT, 256, 16384, 256);
  attn_fwd<<<1024, 256, 0, stream>>>(qkb, vT, po0, po1, pstats);
  attn_merge<<<4096, 256, 0, stream>>>(po0, po1, pstats, obuf);
  // proj + residual -> x2 (f32)
  gemm_bt<2><<<256, 512, 0, stream>>>(obuf, WtP, proj_b, x, x2, 16384, 256, 256);
  ln_fwd<<<4096, 256, 0, stream>>>(x2, ln2_g, ln2_b, h2);
  // fc1 + gelu -> a1 (bf16)
  gemm_bt<3><<<512, 512, 0, stream>>>(h2, Wt1, mlp_b1, nullptr, a1, 16384, 512, 256);
  // fc2 + residual -> out (f32)
  gemm_bt<2><<<256, 512, 0, stream>>>(a1, Wt2, mlp_b2, x2, out, 16384, 256, 512);
}

// Round 10
// 161.240 us; speedup vs baseline: 1.3937x; 1.0588x over previous
//
#include <hip/hip_runtime.h>

typedef __bf16 bf16;
typedef __bf16 bf16x8 __attribute__((ext_vector_type(8)));
typedef __bf16 bf16x4 __attribute__((ext_vector_type(4)));
typedef float  f32x4  __attribute__((ext_vector_type(4)));
typedef unsigned u32x2 __attribute__((ext_vector_type(2)));

typedef __attribute__((address_space(1))) const void GASV;
typedef __attribute__((address_space(3))) void LASV;

__device__ __forceinline__ void gload16(const void* g, void* l) {
  __builtin_amdgcn_global_load_lds((GASV*)g, (LASV*)l, 16, 0, 0);
}

constexpr float CEXP = 0.125f * 1.44269504088896340736f;  // attn scale folded into exp2

// ---------------- fused: weight transposes (blocks 0-511) + layernorm1 (blocks 512-4607) ----
__global__ __launch_bounds__(256) void prep_fused(const float* __restrict__ qkv_w,
                                                  const float* __restrict__ proj_w,
                                                  const float* __restrict__ w1,
                                                  const float* __restrict__ w2,
                                                  bf16* __restrict__ Wtqkv,
                                                  bf16* __restrict__ WtP,
                                                  bf16* __restrict__ Wt1,
                                                  bf16* __restrict__ Wt2,
                                                  const float* __restrict__ x,
                                                  const float* __restrict__ gam,
                                                  const float* __restrict__ bet,
                                                  bf16* __restrict__ hout) {
  __shared__ float td[32][33];
  const int blk = blockIdx.x;
  const int tid = threadIdx.x;
  if (blk >= 512) {   // ---- layernorm path ----
    const int lane = tid & 63;
    const int w = tid >> 6;
    const size_t row = (size_t)(blk - 512) * 4 + w;
    const float4 v = *(const float4*)(x + row * 256 + lane * 4);
    float s1 = v.x + v.y + v.z + v.w;
    float s2 = v.x * v.x + v.y * v.y + v.z * v.z + v.w * v.w;
#pragma unroll
    for (int m = 1; m < 64; m <<= 1) {
      s1 += __shfl_xor(s1, m);
      s2 += __shfl_xor(s2, m);
    }
    const float mu = s1 * (1.0f / 256.0f);
    const float var = s2 * (1.0f / 256.0f) - mu * mu;
    const float rs = rsqrtf(var + 1e-5f);
    const float4 g4 = *(const float4*)(gam + lane * 4);
    const float4 b4 = *(const float4*)(bet + lane * 4);
    bf16x4 o;
    o[0] = (bf16)((v.x - mu) * rs * g4.x + b4.x);
    o[1] = (bf16)((v.y - mu) * rs * g4.y + b4.y);
    o[2] = (bf16)((v.z - mu) * rs * g4.z + b4.z);
    o[3] = (bf16)((v.w - mu) * rs * g4.w + b4.w);
    *(bf16x4*)(hout + row * 256 + lane * 4) = o;
    return;
  }
  // ---- weight transpose path ----
  const int t = blk;
  const float* src;
  bf16* dst;
  int Kin, Nin, kt, nt;
  if (t < 192)      { src = qkv_w; dst = Wtqkv; Kin = 256; Nin = 768; kt = t & 7;          nt = t >> 3; }
  else if (t < 256) { src = proj_w; dst = WtP;  Kin = 256; Nin = 256; kt = (t - 192) & 7;  nt = (t - 192) >> 3; }
  else if (t < 384) { src = w1;    dst = Wt1;   Kin = 256; Nin = 512; kt = (t - 256) & 7;  nt = (t - 256) >> 3; }
  else              { src = w2;    dst = Wt2;   Kin = 512; Nin = 256; kt = (t - 384) & 15; nt = (t - 384) >> 4; }
  {
    const int r = tid >> 3, c4 = (tid & 7) << 2;
    const float4 v = *(const float4*)(src + (size_t)(kt * 32 + r) * Nin + nt * 32 + c4);
    td[r][c4 + 0] = v.x; td[r][c4 + 1] = v.y; td[r][c4 + 2] = v.z; td[r][c4 + 3] = v.w;
  }
  __syncthreads();
  {
    const int n = tid >> 3, k4 = (tid & 7) << 2;
    bf16x4 o;
#pragma unroll
    for (int i = 0; i < 4; ++i) o[i] = (bf16)td[k4 + i][n];
    *(bf16x4*)(dst + (size_t)(nt * 32 + n) * Kin + kt * 32 + k4) = o;
  }
}

// ---------------- layernorm rows of 256 (fp32 in -> bf16 out); 1 wave per row ----------------
__global__ __launch_bounds__(256) void ln_fwd(const float* __restrict__ x,
                                              const float* __restrict__ gam,
                                              const float* __restrict__ bet,
                                              bf16* __restrict__ out) {
  const int lane = threadIdx.x & 63;
  const int w = threadIdx.x >> 6;
  const size_t row = (size_t)blockIdx.x * 4 + w;
  const float4 v = *(const float4*)(x + row * 256 + lane * 4);
  float s1 = v.x + v.y + v.z + v.w;
  float s2 = v.x * v.x + v.y * v.y + v.z * v.z + v.w * v.w;
#pragma unroll
  for (int m = 1; m < 64; m <<= 1) {
    s1 += __shfl_xor(s1, m);
    s2 += __shfl_xor(s2, m);
  }
  const float mu = s1 * (1.0f / 256.0f);
  const float var = s2 * (1.0f / 256.0f) - mu * mu;
  const float rs = rsqrtf(var + 1e-5f);
  const float4 g4 = *(const float4*)(gam + lane * 4);
  const float4 b4 = *(const float4*)(bet + lane * 4);
  bf16x4 o;
  o[0] = (bf16)((v.x - mu) * rs * g4.x + b4.x);
  o[1] = (bf16)((v.y - mu) * rs * g4.y + b4.y);
  o[2] = (bf16)((v.z - mu) * rs * g4.z + b4.z);
  o[3] = (bf16)((v.w - mu) * rs * g4.w + b4.w);
  *(bf16x4*)(out + row * 256 + lane * 4) = o;
}

// ---------------- BT-form GEMM core: 128x128 tile, BK=64, 512 thr (8 waves 2x4) ------------
// Frag-major LDS (all K-loop ds_reads = base + lane*16 + imm). NB=2: classic double-buffer
// with full drain. NB=3: counted vmcnt(4) keeps one tile's loads in flight across barriers.
template <int EPI, int NB>
__device__ __forceinline__ void gemm_core(bf16* __restrict__ ldsA, bf16* __restrict__ ldsB,
                                          const bf16* __restrict__ A,
                                          const bf16* __restrict__ Bt,
                                          const float* __restrict__ bias,
                                          const float* __restrict__ res,
                                          void* __restrict__ outp,
                                          int M, int N, int K, int bid) {
  const int tid = threadIdx.x;
  const int lane = tid & 63;
  const int W = tid >> 6;          // 0..7
  const int wm = W >> 2, wn = W & 3;
  const int qi = lane & 15, g = lane >> 4;
  const int nbm = M >> 7;
  const int bm = bid % nbm;
  const int bn = bid / nbm;
  const int m0 = bm << 7, n0 = bn << 7;
  const int nk = K >> 6;

  const char* asrc[2];
  const char* bsrc[2];
#pragma unroll
  for (int p = 0; p < 2; ++p) {
    const int s = p * 8 + W;
    const int row = (s >> 3) * 64 + ((s >> 1) & 3) * 16 + qi;
    const int kb = (s & 1) * 64 + g * 16;
    asrc[p] = (const char*)(A + (size_t)(m0 + row) * K) + kb;
    bsrc[p] = (const char*)(Bt + (size_t)(n0 + row) * K) + kb;
  }

  f32x4 acc[4][2];
#pragma unroll
  for (int i = 0; i < 4; ++i)
#pragma unroll
    for (int j = 0; j < 2; ++j) acc[i][j] = (f32x4){0.f, 0.f, 0.f, 0.f};

  auto stage = [&](int sl) {
#pragma unroll
    for (int p = 0; p < 2; ++p) {
      gload16(asrc[p], (char*)ldsA + sl * 16384 + (p * 8 + W) * 1024);
      gload16(bsrc[p], (char*)ldsB + sl * 16384 + (p * 8 + W) * 1024);
      asrc[p] += 128;
      bsrc[p] += 128;
    }
  };

  if constexpr (NB == 2) {
    stage(0);
    asm volatile("s_waitcnt vmcnt(0)" ::: "memory");
  } else {
    stage(0);
    stage(1);
    asm volatile("s_waitcnt vmcnt(4)" ::: "memory");   // tile0 done, tile1 in flight
  }
  __builtin_amdgcn_s_barrier();

  int cur = 0, nxt = (NB == 2) ? 1 : 2;
  for (int t = 0; t < nk; ++t) {
    if constexpr (NB == 2) {
      if (t + 1 < nk) stage(nxt);
    }
    const char* pa = (const char*)ldsA + cur * 16384 + wm * 8192 + lane * 16;
    const char* pb = (const char*)ldsB + cur * 16384 + lane * 16;
    bf16x8 av[4][2], bv[2][2];
#pragma unroll
    for (int f = 0; f < 4; ++f)
#pragma unroll
      for (int ks = 0; ks < 2; ++ks)
        av[f][ks] = *(const bf16x8*)(pa + (f * 2 + ks) * 1024);
#pragma unroll
    for (int fn = 0; fn < 2; ++fn)
#pragma unroll
      for (int ks = 0; ks < 2; ++ks) {
        const int r16 = wn * 2 + fn;
        bv[fn][ks] = *(const bf16x8*)(pb + ((r16 >> 2) * 8 + (r16 & 3) * 2 + ks) * 1024);
      }
    if constexpr (NB == 3) {
      if (t + 2 < nk) stage(nxt);   // issue 2-ahead; lands while tile t / t+1 compute
    }
    __builtin_amdgcn_s_setprio(1);
#pragma unroll
    for (int fm = 0; fm < 4; ++fm)
#pragma unroll
      for (int fn = 0; fn < 2; ++fn) {
        acc[fm][fn] = __builtin_amdgcn_mfma_f32_16x16x32_bf16(av[fm][0], bv[fn][0], acc[fm][fn], 0, 0, 0);
        acc[fm][fn] = __builtin_amdgcn_mfma_f32_16x16x32_bf16(av[fm][1], bv[fn][1], acc[fm][fn], 0, 0, 0);
      }
    __builtin_amdgcn_s_setprio(0);
    if constexpr (NB == 2) {
      asm volatile("s_waitcnt vmcnt(0)" ::: "memory");
    } else {
      if (t + 2 < nk) {
        asm volatile("s_waitcnt vmcnt(4)" ::: "memory");  // drain only tile t+1's loads
      } else {
        asm volatile("s_waitcnt vmcnt(0)" ::: "memory");  // tail
      }
    }
    __builtin_amdgcn_s_barrier();
    cur = (cur == NB - 1) ? 0 : cur + 1;
    nxt = (nxt == NB - 1) ? 0 : nxt + 1;
  }

#pragma unroll
  for (int fm = 0; fm < 4; ++fm)
#pragma unroll
    for (int fn = 0; fn < 2; ++fn) {
      const int r0 = m0 + wm * 64 + fm * 16 + g * 4;
      const int c = n0 + wn * 32 + fn * 16 + qi;
#pragma unroll
      for (int j = 0; j < 4; ++j) {
        const int r = r0 + j;
        const float v = acc[fm][fn][j];
        if constexpr (EPI == 0) {
          ((bf16*)outp)[(size_t)r * N + c] = (bf16)(v + bias[c]);
        } else if constexpr (EPI == 1) {
          ((bf16*)outp)[(size_t)r * 2048 + ((size_t)(c >> 11)) * 524288 + (c & 2047)] =
              (bf16)(v + bias[r]);
        } else if constexpr (EPI == 2) {
          ((float*)outp)[(size_t)r * N + c] = v + bias[c] + res[(size_t)r * N + c];
        } else {
          const float u = v + bias[c];
          ((bf16*)outp)[(size_t)r * N + c] = (bf16)(u * 0.5f * (1.0f + erff(u * 0.70710678118f)));
        }
      }
    }
}

// fused QK-gemm (blocks 0-511) + V-gemm (blocks 512-767), both NB=2 (shared 64KB LDS)
__global__ __launch_bounds__(512) void gemm_qkv_fused(const bf16* __restrict__ h,
                                                      const bf16* __restrict__ Wtqkv,
                                                      const float* __restrict__ qkv_b,
                                                      bf16* __restrict__ qkb,
                                                      bf16* __restrict__ vT) {
  __shared__ bf16 ldsA[2 * 8192];
  __shared__ bf16 ldsB[2 * 8192];
  const int bid = (int)blockIdx.x;
  if (bid < 512) {
    gemm_core<0, 2>(ldsA, ldsB, h, Wtqkv, qkv_b, nullptr, qkb, 16384, 512, 256, bid);
  } else {
    gemm_core<1, 2>(ldsA, ldsB, Wtqkv + 512 * 256, h, qkv_b + 512, nullptr, vT,
                    256, 16384, 256, bid - 512);
  }
}

template <int EPI, int NB>
__global__ __launch_bounds__(512) void gemm_one(const bf16* __restrict__ A,
                                                const bf16* __restrict__ Bt,
                                                const float* __restrict__ bias,
                                                const float* __restrict__ res,
                                                void* __restrict__ outp,
                                                int M, int N, int K) {
  __shared__ bf16 ldsA[NB * 8192];
  __shared__ bf16 ldsB[NB * 8192];
  gemm_core<EPI, NB>(ldsA, ldsB, A, Bt, bias, res, outp, M, N, K, (int)blockIdx.x);
}

// ---------------- flash attention v5 (frozen: r7 version, 92 us) ---------------------------
__global__ __launch_bounds__(256) void attn_fwd(const bf16* __restrict__ qk,
                                                const bf16* __restrict__ vT,
                                                bf16* __restrict__ po0,
                                                bf16* __restrict__ po1,
                                                float* __restrict__ pstats) {
  __shared__ bf16 Kl[2][4096];
  __shared__ bf16 Vl[2][4096];
  __shared__ bf16 Pl[4][1024];
  const int tid = threadIdx.x;
  const int lane = tid & 63;
  const int w = tid >> 6;
  const int g = lane >> 4;
  const int qi = lane & 15;
  const int bid = (int)blockIdx.x;
  const int bh = bid & 31;
  const int qt = (bid >> 5) & 15;
  const int s = bid >> 9;
  const int b = bh >> 2, h = bh & 3;

  const size_t qrow0 = (size_t)b * 2048 + qt * 128 + w * 32 + qi;
  bf16x8 qf[2][2];
#pragma unroll
  for (int f = 0; f < 2; ++f) {
    const bf16* qp = qk + (qrow0 + f * 16) * 512 + h * 64 + g * 8;
    qf[f][0] = *(const bf16x8*)qp;
    qf[f][1] = *(const bf16x8*)(qp + 32);
  }

  float mrun[2] = {0.f, 0.f};
  float lsum[2] = {0.f, 0.f};
  f32x4 o[4][2];
#pragma unroll
  for (int i = 0; i < 4; ++i)
#pragma unroll
    for (int f = 0; f < 2; ++f) o[i][f] = (f32x4){0.f, 0.f, 0.f, 0.f};

  constexpr float THR = 8.0f / CEXP;

  const char* kbase = (const char*)qk + ((size_t)b * 2048) * 1024 + 512 + h * 128 +
                      (size_t)s * 16 * 65536;
  const char* vbase = (const char*)vT + (size_t)bh * 262144 + (size_t)s * 16 * 128;
  const char* ks[2];
  const char* vs[2];
#pragma unroll
  for (int i = 0; i < 2; ++i) {
    const int fk = i * 2 + (w >> 1);
    const int half = w & 1;
    ks[i] = kbase + (fk * 16 + qi) * 1024 + half * 64 + g * 16;
    vs[i] = vbase + (size_t)(fk * 16 + qi) * 4096 + half * 64 + g * 16;
  }
  char* const pw = (char*)&Pl[w][0];
  int paddrb[2];
#pragma unroll
  for (int bb = 0; bb < 2; ++bb)
    paddrb[bb] = (bb * 2 + (g >> 1)) * 256 + qi * 16 + (g & 1) * 8;
  const char* const prd = pw + lane * 16;

  auto stage = [&](int slot) {
    char* kd = (char*)&Kl[0][0] + slot * 8192 + w * 1024;
    char* vd = (char*)&Vl[0][0] + slot * 8192 + w * 1024;
    gload16(ks[0], kd);
    gload16(ks[1], kd + 4096);
    gload16(vs[0], vd);
    gload16(vs[1], vd + 4096);
    ks[0] += 65536; ks[1] += 65536;
    vs[0] += 128;   vs[1] += 128;
  };

  stage(0);
  asm volatile("s_waitcnt vmcnt(0)" ::: "memory");
  __builtin_amdgcn_s_barrier();

  for (int t = 0; t < 16; ++t) {
    if (t < 15) stage((t + 1) & 1);
    const char* kb = (const char*)&Kl[0][0] + (t & 1) * 8192 + lane * 16;
    f32x4 st[4][2];
    __builtin_amdgcn_s_setprio(1);
#pragma unroll
    for (int fk = 0; fk < 4; ++fk) {
      const bf16x8 k0 = *(const bf16x8*)(kb + fk * 2048);
      const bf16x8 k1 = *(const bf16x8*)(kb + fk * 2048 + 1024);
#pragma unroll
      for (int f = 0; f < 2; ++f) {
        f32x4 z = (f32x4){0.f, 0.f, 0.f, 0.f};
        st[fk][f] = __builtin_amdgcn_mfma_f32_16x16x32_bf16(k0, qf[f][0], z, 0, 0, 0);
        st[fk][f] = __builtin_amdgcn_mfma_f32_16x16x32_bf16(k1, qf[f][1], st[fk][f], 0, 0, 0);
      }
    }
    __builtin_amdgcn_s_setprio(0);
    float pmax[2];
#pragma unroll
    for (int f = 0; f < 2; ++f) {
      float m0 = fmaxf(fmaxf(st[0][f][0], st[0][f][1]), fmaxf(st[0][f][2], st[0][f][3]));
      float m1 = fmaxf(fmaxf(st[1][f][0], st[1][f][1]), fmaxf(st[1][f][2], st[1][f][3]));
      float m2 = fmaxf(fmaxf(st[2][f][0], st[2][f][1]), fmaxf(st[2][f][2], st[2][f][3]));
      float m3 = fmaxf(fmaxf(st[3][f][0], st[3][f][1]), fmaxf(st[3][f][2], st[3][f][3]));
      pmax[f] = fmaxf(fmaxf(m0, m1), fmaxf(m2, m3));
    }
    if (!__all(pmax[0] <= mrun[0] + THR && pmax[1] <= mrun[1] + THR)) {
#pragma unroll
      for (int f = 0; f < 2; ++f) {
        float mt = fmaxf(pmax[f], __shfl_xor(pmax[f], 16));
        mt = fmaxf(mt, __shfl_xor(mt, 32));
        const float mnew = fmaxf(mrun[f], mt);
        const float alpha = exp2f(CEXP * (mrun[f] - mnew));
        lsum[f] *= alpha;
#pragma unroll
        for (int fd = 0; fd < 4; ++fd)
#pragma unroll
          for (int j = 0; j < 4; ++j) o[fd][f][j] *= alpha;
        mrun[f] = mnew;
      }
    }
    unsigned pk[4][2][2];
#pragma unroll
    for (int f = 0; f < 2; ++f) {
      const float negcm = -CEXP * mrun[f];
      float ts = 0.f;
#pragma unroll
      for (int fk = 0; fk < 4; ++fk)
#pragma unroll
        for (int jp = 0; jp < 2; ++jp) {
          const float p0 = exp2f(fmaf(st[fk][f][2 * jp], CEXP, negcm));
          const float p1 = exp2f(fmaf(st[fk][f][2 * jp + 1], CEXP, negcm));
          ts += p0 + p1;
          union { bf16 h2[2]; unsigned u; } cv;
          cv.h2[0] = (bf16)p0;
          cv.h2[1] = (bf16)p1;
          pk[fk][f][jp] = cv.u;
        }
      lsum[f] += ts;
    }
    const char* vb = (const char*)&Vl[0][0] + (t & 1) * 8192 + lane * 16;
#pragma unroll
    for (int ksl = 0; ksl < 2; ++ksl) {
#pragma unroll
      for (int bb = 0; bb < 2; ++bb) {
        const int fk = 2 * ksl + bb;
#pragma unroll
        for (int f = 0; f < 2; ++f) {
          u32x2 pv2;
          pv2[0] = pk[fk][f][0];
          pv2[1] = pk[fk][f][1];
          *(u32x2*)(pw + f * 1024 + paddrb[bb]) = pv2;
        }
      }
      bf16x8 pa[2];
#pragma unroll
      for (int f = 0; f < 2; ++f) pa[f] = *(const bf16x8*)(prd + f * 1024);
      __builtin_amdgcn_s_setprio(1);
#pragma unroll
      for (int fd = 0; fd < 4; ++fd) {
        const bf16x8 vv = *(const bf16x8*)(vb + fd * 2048 + ksl * 1024);
#pragma unroll
        for (int f = 0; f < 2; ++f)
          o[fd][f] = __builtin_amdgcn_mfma_f32_16x16x32_bf16(vv, pa[f], o[fd][f], 0, 0, 0);
      }
      __builtin_amdgcn_s_setprio(0);
    }
    asm volatile("s_waitcnt vmcnt(0)" ::: "memory");
    __builtin_amdgcn_s_barrier();
  }

#pragma unroll
  for (int f = 0; f < 2; ++f) {
    float l = lsum[f];
    l += __shfl_xor(l, 16);
    l += __shfl_xor(l, 32);
    lsum[f] = l;
  }
  if (g == 0) {
#pragma unroll
    for (int f = 0; f < 2; ++f) {
      float2 sv;
      sv.x = mrun[f];
      sv.y = lsum[f];
      *(float2*)(pstats + (((size_t)s * 32 + bh) * 2048 + qt * 128 + w * 32 + f * 16 + qi) * 2) = sv;
    }
  }
  bf16* const pob = s ? po1 : po0;
#pragma unroll
  for (int f = 0; f < 2; ++f) {
    bf16* const orow = pob + (qrow0 + f * 16) * 256 + h * 64 + g * 4;
#pragma unroll
    for (int fd = 0; fd < 4; ++fd) {
      bf16x4 ov;
#pragma unroll
      for (int j = 0; j < 4; ++j) ov[j] = (bf16)o[fd][f][j];
      *(bf16x4*)(orow + fd * 16) = ov;
    }
  }
}

// ---------------- flash merge of the two kv-half partials ----------------------------------
__global__ __launch_bounds__(256) void attn_merge(const bf16* __restrict__ po0,
                                                  const bf16* __restrict__ po1,
                                                  const float* __restrict__ pstats,
                                                  bf16* __restrict__ ob) {
  const int idx = blockIdx.x * 256 + threadIdx.x;   // 16384*64
  const int r = idx >> 6;
  const int cq = (idx & 63) * 4;
  const int h = cq >> 6;
  const int bh = (r >> 11) * 4 + h;
  const int ql = r & 2047;
  const float2 s0 = *(const float2*)(pstats + (((size_t)bh) * 2048 + ql) * 2);
  const float2 s1 = *(const float2*)(pstats + (((size_t)32 + bh) * 2048 + ql) * 2);
  const float M = fmaxf(s0.x, s1.x);
  const float a0 = exp2f(CEXP * (s0.x - M));
  const float a1 = exp2f(CEXP * (s1.x - M));
  const float inv = 1.0f / (s0.y * a0 + s1.y * a1);
  const bf16x4 p0 = *(const bf16x4*)(po0 + (size_t)r * 256 + cq);
  const bf16x4 p1 = *(const bf16x4*)(po1 + (size_t)r * 256 + cq);
  bf16x4 ov;
#pragma unroll
  for (int j = 0; j < 4; ++j)
    ov[j] = (bf16)(((float)p0[j] * a0 + (float)p1[j] * a1) * inv);
  *(bf16x4*)(ob + (size_t)r * 256 + cq) = ov;
}

extern "C" void kernel_launch(void* const* d_in, const int* in_sizes, int n_in,
                              void* d_out, int out_size, void* d_ws, size_t ws_size,
                              hipStream_t stream) {
  const float* x      = (const float*)d_in[0];
  const float* qkv_w  = (const float*)d_in[1];
  const float* qkv_b  = (const float*)d_in[2];
  const float* proj_w = (const float*)d_in[3];
  const float* proj_b = (const float*)d_in[4];
  const float* ln1_g  = (const float*)d_in[5];
  const float* ln1_b  = (const float*)d_in[6];
  const float* ln2_g  = (const float*)d_in[7];
  const float* ln2_b  = (const float*)d_in[8];
  const float* mlp_w1 = (const float*)d_in[9];
  const float* mlp_b1 = (const float*)d_in[10];
  const float* mlp_w2 = (const float*)d_in[11];
  const float* mlp_b2 = (const float*)d_in[12];
  float* out = (float*)d_out;

  char* ws = (char*)d_ws;
  bf16* Wtqkv = (bf16*)(ws);              // [768][256]   393216 B
  bf16* WtP   = (bf16*)(ws + 393216);     // [256][256]   131072 B
  bf16* Wt1   = (bf16*)(ws + 524288);     // [512][256]   262144 B
  bf16* Wt2   = (bf16*)(ws + 786432);     // [256][512]   262144 B
  bf16* h     = (bf16*)(ws + 1048576);    // [16384][256] 8388608 B  (ln1 out; dead after V gemm)
  bf16* qkb   = (bf16*)(ws + 9437184);    // [16384][512] 16777216 B
  bf16* vT    = (bf16*)(ws + 26214400);   // [32][64][2048] 8388608 B (dead after attn -> obuf)
  bf16* po1   = (bf16*)(ws + 34603008);   // [16384][256] 8388608 B  (kv-half-1 partial)
  float* x2   = (float*)(ws + 42991616);  // [16384][256] 16777216 B
  float* pstats = (float*)(ws + 59768832);// [2][32][2048][2] f32  1 MB  (total 60.8 MB)
  bf16* po0  = h;            // kv-half-0 partial reuses h (dead once attn starts)
  bf16* obuf = vT;           // merged attn output reuses vT (dead after attn)
  bf16* a1 = qkb;            // fc1 out reuses qkb (dead after attn)
  bf16* h2 = h;              // ln2 out reuses h region (po0 dead after merge)

  // wconv (512 blocks) + ln1 (4096 blocks) fused
  prep_fused<<<4608, 256, 0, stream>>>(qkv_w, proj_w, mlp_w1, mlp_w2, Wtqkv, WtP, Wt1, Wt2,
                                       x, ln1_g, ln1_b, h);
  // QK gemm (512 blocks) + V^T gemm (256 blocks) in one launch
  gemm_qkv_fused<<<768, 512, 0, stream>>>(h, Wtqkv, qkv_b, qkb, vT);
  attn_fwd<<<1024, 256, 0, stream>>>(qkb, vT, po0, po1, pstats);
  attn_merge<<<4096, 256, 0, stream>>>(po0, po1, pstats, obuf);
  // proj + residual -> x2 (f32)  [3-deep counted-vmcnt pipeline]
  gemm_one<2, 3><<<256, 512, 0, stream>>>(obuf, WtP, proj_b, x, x2, 16384, 256, 256);
  ln_fwd<<<4096, 256, 0, stream>>>(x2, ln2_g, ln2_b, h2);
  // fc1 + gelu -> a1 (bf16)
  gemm_one<3, 2><<<512, 512, 0, stream>>>(h2, Wt1, mlp_b1, nullptr, a1, 16384, 512, 256);
  // fc2 + residual -> out (f32)  [3-deep counted-vmcnt pipeline]
  gemm_one<2, 3><<<256, 512, 0, stream>>>(a1, Wt2, mlp_b2, x2, out, 16384, 256, 512);
}

// Round 11
// 160.504 us; speedup vs baseline: 1.4001x; 1.0046x over previous
//
#include <hip/hip_runtime.h>

typedef __bf16 bf16;
typedef __bf16 bf16x8 __attribute__((ext_vector_type(8)));
typedef __bf16 bf16x4 __attribute__((ext_vector_type(4)));
typedef float  f32x4  __attribute__((ext_vector_type(4)));
typedef unsigned u32x2 __attribute__((ext_vector_type(2)));

typedef __attribute__((address_space(1))) const void GASV;
typedef __attribute__((address_space(3))) void LASV;

__device__ __forceinline__ void gload16(const void* g, void* l) {
  __builtin_amdgcn_global_load_lds((GASV*)g, (LASV*)l, 16, 0, 0);
}

constexpr float CEXP = 0.125f * 1.44269504088896340736f;  // attn scale folded into exp2

// ---------------- fused: weight transposes (blocks 0-511) + layernorm1 (blocks 512-4607) ----
__global__ __launch_bounds__(256) void prep_fused(const float* __restrict__ qkv_w,
                                                  const float* __restrict__ proj_w,
                                                  const float* __restrict__ w1,
                                                  const float* __restrict__ w2,
                                                  bf16* __restrict__ Wtqkv,
                                                  bf16* __restrict__ WtP,
                                                  bf16* __restrict__ Wt1,
                                                  bf16* __restrict__ Wt2,
                                                  const float* __restrict__ x,
                                                  const float* __restrict__ gam,
                                                  const float* __restrict__ bet,
                                                  bf16* __restrict__ hout) {
  __shared__ float td[32][33];
  const int blk = blockIdx.x;
  const int tid = threadIdx.x;
  if (blk >= 512) {   // ---- layernorm path ----
    const int lane = tid & 63;
    const int w = tid >> 6;
    const size_t row = (size_t)(blk - 512) * 4 + w;
    const float4 v = *(const float4*)(x + row * 256 + lane * 4);
    float s1 = v.x + v.y + v.z + v.w;
    float s2 = v.x * v.x + v.y * v.y + v.z * v.z + v.w * v.w;
#pragma unroll
    for (int m = 1; m < 64; m <<= 1) {
      s1 += __shfl_xor(s1, m);
      s2 += __shfl_xor(s2, m);
    }
    const float mu = s1 * (1.0f / 256.0f);
    const float var = s2 * (1.0f / 256.0f) - mu * mu;
    const float rs = rsqrtf(var + 1e-5f);
    const float4 g4 = *(const float4*)(gam + lane * 4);
    const float4 b4 = *(const float4*)(bet + lane * 4);
    bf16x4 o;
    o[0] = (bf16)((v.x - mu) * rs * g4.x + b4.x);
    o[1] = (bf16)((v.y - mu) * rs * g4.y + b4.y);
    o[2] = (bf16)((v.z - mu) * rs * g4.z + b4.z);
    o[3] = (bf16)((v.w - mu) * rs * g4.w + b4.w);
    *(bf16x4*)(hout + row * 256 + lane * 4) = o;
    return;
  }
  // ---- weight transpose path ----
  const int t = blk;
  const float* src;
  bf16* dst;
  int Kin, Nin, kt, nt;
  if (t < 192)      { src = qkv_w; dst = Wtqkv; Kin = 256; Nin = 768; kt = t & 7;          nt = t >> 3; }
  else if (t < 256) { src = proj_w; dst = WtP;  Kin = 256; Nin = 256; kt = (t - 192) & 7;  nt = (t - 192) >> 3; }
  else if (t < 384) { src = w1;    dst = Wt1;   Kin = 256; Nin = 512; kt = (t - 256) & 7;  nt = (t - 256) >> 3; }
  else              { src = w2;    dst = Wt2;   Kin = 512; Nin = 256; kt = (t - 384) & 15; nt = (t - 384) >> 4; }
  {
    const int r = tid >> 3, c4 = (tid & 7) << 2;
    const float4 v = *(const float4*)(src + (size_t)(kt * 32 + r) * Nin + nt * 32 + c4);
    td[r][c4 + 0] = v.x; td[r][c4 + 1] = v.y; td[r][c4 + 2] = v.z; td[r][c4 + 3] = v.w;
  }
  __syncthreads();
  {
    const int n = tid >> 3, k4 = (tid & 7) << 2;
    bf16x4 o;
#pragma unroll
    for (int i = 0; i < 4; ++i) o[i] = (bf16)td[k4 + i][n];
    *(bf16x4*)(dst + (size_t)(nt * 32 + n) * Kin + kt * 32 + k4) = o;
  }
}

// ---------------- layernorm rows of 256 (fp32 in -> bf16 out); 1 wave per row ----------------
__global__ __launch_bounds__(256) void ln_fwd(const float* __restrict__ x,
                                              const float* __restrict__ gam,
                                              const float* __restrict__ bet,
                                              bf16* __restrict__ out) {
  const int lane = threadIdx.x & 63;
  const int w = threadIdx.x >> 6;
  const size_t row = (size_t)blockIdx.x * 4 + w;
  const float4 v = *(const float4*)(x + row * 256 + lane * 4);
  float s1 = v.x + v.y + v.z + v.w;
  float s2 = v.x * v.x + v.y * v.y + v.z * v.z + v.w * v.w;
#pragma unroll
  for (int m = 1; m < 64; m <<= 1) {
    s1 += __shfl_xor(s1, m);
    s2 += __shfl_xor(s2, m);
  }
  const float mu = s1 * (1.0f / 256.0f);
  const float var = s2 * (1.0f / 256.0f) - mu * mu;
  const float rs = rsqrtf(var + 1e-5f);
  const float4 g4 = *(const float4*)(gam + lane * 4);
  const float4 b4 = *(const float4*)(bet + lane * 4);
  bf16x4 o;
  o[0] = (bf16)((v.x - mu) * rs * g4.x + b4.x);
  o[1] = (bf16)((v.y - mu) * rs * g4.y + b4.y);
  o[2] = (bf16)((v.z - mu) * rs * g4.z + b4.z);
  o[3] = (bf16)((v.w - mu) * rs * g4.w + b4.w);
  *(bf16x4*)(out + row * 256 + lane * 4) = o;
}

// ---------------- BT-form GEMM core: 128x128 tile, BK=64, 512 thr (8 waves 2x4) ------------
// Frag-major LDS (all K-loop ds_reads = base + lane*16 + imm). NB=2: classic double-buffer
// with full drain. NB=3: counted vmcnt(4) keeps one tile's loads in flight across barriers.
template <int EPI, int NB>
__device__ __forceinline__ void gemm_core(bf16* __restrict__ ldsA, bf16* __restrict__ ldsB,
                                          const bf16* __restrict__ A,
                                          const bf16* __restrict__ Bt,
                                          const float* __restrict__ bias,
                                          const float* __restrict__ res,
                                          void* __restrict__ outp,
                                          int M, int N, int K, int bid) {
  const int tid = threadIdx.x;
  const int lane = tid & 63;
  const int W = tid >> 6;          // 0..7
  const int wm = W >> 2, wn = W & 3;
  const int qi = lane & 15, g = lane >> 4;
  const int nbm = M >> 7;
  const int bm = bid % nbm;
  const int bn = bid / nbm;
  const int m0 = bm << 7, n0 = bn << 7;
  const int nk = K >> 6;

  const char* asrc[2];
  const char* bsrc[2];
#pragma unroll
  for (int p = 0; p < 2; ++p) {
    const int s = p * 8 + W;
    const int row = (s >> 3) * 64 + ((s >> 1) & 3) * 16 + qi;
    const int kb = (s & 1) * 64 + g * 16;
    asrc[p] = (const char*)(A + (size_t)(m0 + row) * K) + kb;
    bsrc[p] = (const char*)(Bt + (size_t)(n0 + row) * K) + kb;
  }

  f32x4 acc[4][2];
#pragma unroll
  for (int i = 0; i < 4; ++i)
#pragma unroll
    for (int j = 0; j < 2; ++j) acc[i][j] = (f32x4){0.f, 0.f, 0.f, 0.f};

  auto stage = [&](int sl) {
#pragma unroll
    for (int p = 0; p < 2; ++p) {
      gload16(asrc[p], (char*)ldsA + sl * 16384 + (p * 8 + W) * 1024);
      gload16(bsrc[p], (char*)ldsB + sl * 16384 + (p * 8 + W) * 1024);
      asrc[p] += 128;
      bsrc[p] += 128;
    }
  };

  if constexpr (NB == 2) {
    stage(0);
    asm volatile("s_waitcnt vmcnt(0)" ::: "memory");
  } else {
    stage(0);
    stage(1);
    asm volatile("s_waitcnt vmcnt(4)" ::: "memory");   // tile0 done, tile1 in flight
  }
  __builtin_amdgcn_s_barrier();

  int cur = 0, nxt = (NB == 2) ? 1 : 2;
  for (int t = 0; t < nk; ++t) {
    if constexpr (NB == 2) {
      if (t + 1 < nk) stage(nxt);
    }
    const char* pa = (const char*)ldsA + cur * 16384 + wm * 8192 + lane * 16;
    const char* pb = (const char*)ldsB + cur * 16384 + lane * 16;
    bf16x8 av[4][2], bv[2][2];
#pragma unroll
    for (int f = 0; f < 4; ++f)
#pragma unroll
      for (int ks = 0; ks < 2; ++ks)
        av[f][ks] = *(const bf16x8*)(pa + (f * 2 + ks) * 1024);
#pragma unroll
    for (int fn = 0; fn < 2; ++fn)
#pragma unroll
      for (int ks = 0; ks < 2; ++ks) {
        const int r16 = wn * 2 + fn;
        bv[fn][ks] = *(const bf16x8*)(pb + ((r16 >> 2) * 8 + (r16 & 3) * 2 + ks) * 1024);
      }
    if constexpr (NB == 3) {
      if (t + 2 < nk) stage(nxt);   // issue 2-ahead; lands while tile t / t+1 compute
    }
    __builtin_amdgcn_s_setprio(1);
#pragma unroll
    for (int fm = 0; fm < 4; ++fm)
#pragma unroll
      for (int fn = 0; fn < 2; ++fn) {
        acc[fm][fn] = __builtin_amdgcn_mfma_f32_16x16x32_bf16(av[fm][0], bv[fn][0], acc[fm][fn], 0, 0, 0);
        acc[fm][fn] = __builtin_amdgcn_mfma_f32_16x16x32_bf16(av[fm][1], bv[fn][1], acc[fm][fn], 0, 0, 0);
      }
    __builtin_amdgcn_s_setprio(0);
    if constexpr (NB == 2) {
      asm volatile("s_waitcnt vmcnt(0)" ::: "memory");
    } else {
      if (t + 2 < nk) {
        asm volatile("s_waitcnt vmcnt(4)" ::: "memory");  // drain only tile t+1's loads
      } else {
        asm volatile("s_waitcnt vmcnt(0)" ::: "memory");  // tail
      }
    }
    __builtin_amdgcn_s_barrier();
    cur = (cur == NB - 1) ? 0 : cur + 1;
    nxt = (nxt == NB - 1) ? 0 : nxt + 1;
  }

#pragma unroll
  for (int fm = 0; fm < 4; ++fm)
#pragma unroll
    for (int fn = 0; fn < 2; ++fn) {
      const int r0 = m0 + wm * 64 + fm * 16 + g * 4;
      const int c = n0 + wn * 32 + fn * 16 + qi;
#pragma unroll
      for (int j = 0; j < 4; ++j) {
        const int r = r0 + j;
        const float v = acc[fm][fn][j];
        if constexpr (EPI == 0) {
          ((bf16*)outp)[(size_t)r * N + c] = (bf16)(v + bias[c]);
        } else if constexpr (EPI == 1) {
          ((bf16*)outp)[(size_t)r * 2048 + ((size_t)(c >> 11)) * 524288 + (c & 2047)] =
              (bf16)(v + bias[r]);
        } else if constexpr (EPI == 2) {
          ((float*)outp)[(size_t)r * N + c] = v + bias[c] + res[(size_t)r * N + c];
        } else {
          const float u = v + bias[c];
          ((bf16*)outp)[(size_t)r * N + c] = (bf16)(u * 0.5f * (1.0f + erff(u * 0.70710678118f)));
        }
      }
    }
}

// fused QK-gemm (blocks 0-511) + V-gemm (blocks 512-767), both NB=2 (shared 64KB LDS)
__global__ __launch_bounds__(512) void gemm_qkv_fused(const bf16* __restrict__ h,
                                                      const bf16* __restrict__ Wtqkv,
                                                      const float* __restrict__ qkv_b,
                                                      bf16* __restrict__ qkb,
                                                      bf16* __restrict__ vT) {
  __shared__ bf16 ldsA[2 * 8192];
  __shared__ bf16 ldsB[2 * 8192];
  const int bid = (int)blockIdx.x;
  if (bid < 512) {
    gemm_core<0, 2>(ldsA, ldsB, h, Wtqkv, qkv_b, nullptr, qkb, 16384, 512, 256, bid);
  } else {
    gemm_core<1, 2>(ldsA, ldsB, Wtqkv + 512 * 256, h, qkv_b + 512, nullptr, vT,
                    256, 16384, 256, bid - 512);
  }
}

template <int EPI, int NB>
__global__ __launch_bounds__(512) void gemm_one(const bf16* __restrict__ A,
                                                const bf16* __restrict__ Bt,
                                                const float* __restrict__ bias,
                                                const float* __restrict__ res,
                                                void* __restrict__ outp,
                                                int M, int N, int K) {
  __shared__ bf16 ldsA[NB * 8192];
  __shared__ bf16 ldsB[NB * 8192];
  gemm_core<EPI, NB>(ldsA, ldsB, A, Bt, bias, res, outp, M, N, K, (int)blockIdx.x);
}

// ---------------- proj GEMM with flash-merge fused into A-staging --------------------------
// A[r][c] = (po0[r][c]*a0 + po1[r][c]*a1)/l  where (a,l) from pstats, head = K-tile index.
// MAload issues reg loads BEFORE tile t's MFMA (latency hides under compute, T14);
// MAwrite merges + ds_writes after. B path unchanged gload_lds. Out: f32 + bias + residual.
__global__ __launch_bounds__(512) void gemm_proj_merge(const bf16* __restrict__ po0,
                                                       const bf16* __restrict__ po1,
                                                       const float* __restrict__ pstats,
                                                       const bf16* __restrict__ Bt,
                                                       const float* __restrict__ bias,
                                                       const float* __restrict__ res,
                                                       float* __restrict__ outp) {
  __shared__ bf16 Al[2][8192];
  __shared__ bf16 Bl[2][8192];
  const int tid = threadIdx.x;
  const int lane = tid & 63;
  const int W = tid >> 6;
  const int wm = W >> 2, wn = W & 3;
  const int qi = lane & 15, g = lane >> 4;
  const int bm = (int)blockIdx.x & 127;   // nbm = 128 (M=16384)
  const int bn = (int)blockIdx.x >> 7;    // N=256 -> 2
  const int m0 = bm << 7, n0 = bn << 7;

  int rowg[2];
  const char* asrc[2];
  const char* bsrc[2];
#pragma unroll
  for (int p = 0; p < 2; ++p) {
    const int s = p * 8 + W;
    const int row = (s >> 3) * 64 + ((s >> 1) & 3) * 16 + qi;
    const int kb = (s & 1) * 64 + g * 16;
    rowg[p] = m0 + row;
    asrc[p] = (const char*)po0 + (size_t)(m0 + row) * 512 + kb;
    bsrc[p] = (const char*)(Bt + (size_t)(n0 + row) * 256) + kb;
  }
  const size_t dpo = (size_t)((const char*)po1 - (const char*)po0);

  f32x4 acc[4][2];
#pragma unroll
  for (int i = 0; i < 4; ++i)
#pragma unroll
    for (int j = 0; j < 2; ++j) acc[i][j] = (f32x4){0.f, 0.f, 0.f, 0.f};

  bf16x8 pa0v[2], pa1v[2];
  float2 sst0[2], sst1[2];

  auto MAload = [&](int t) {
#pragma unroll
    for (int p = 0; p < 2; ++p) {
      gload16(bsrc[p], (char*)&Bl[t & 1][0] + (p * 8 + W) * 1024);
      bsrc[p] += 128;
      pa0v[p] = *(const bf16x8*)(asrc[p]);
      pa1v[p] = *(const bf16x8*)(asrc[p] + dpo);
      asrc[p] += 128;
      const int bh = ((rowg[p] >> 11) << 2) + t;   // head == K-tile index
      const int ql = rowg[p] & 2047;
      sst0[p] = *(const float2*)(pstats + ((size_t)bh * 2048 + ql) * 2);
      sst1[p] = *(const float2*)(pstats + ((size_t)(bh + 32) * 2048 + ql) * 2);
    }
  };
  auto MAwrite = [&](int t) {
#pragma unroll
    for (int p = 0; p < 2; ++p) {
      const float mx = fmaxf(sst0[p].x, sst1[p].x);
      float a0 = exp2f(CEXP * (sst0[p].x - mx));
      float a1 = exp2f(CEXP * (sst1[p].x - mx));
      const float inv = 1.0f / (sst0[p].y * a0 + sst1[p].y * a1);
      a0 *= inv;
      a1 *= inv;
      bf16x8 wv;
#pragma unroll
      for (int j = 0; j < 8; ++j)
        wv[j] = (bf16)((float)pa0v[p][j] * a0 + (float)pa1v[p][j] * a1);
      *(bf16x8*)((char*)&Al[t & 1][0] + (p * 8 + W) * 1024 + lane * 16) = wv;
    }
  };

  MAload(0);
  MAwrite(0);
  asm volatile("s_waitcnt vmcnt(0) lgkmcnt(0)" ::: "memory");
  __builtin_amdgcn_s_barrier();

  for (int t = 0; t < 4; ++t) {
    if (t + 1 < 4) MAload(t + 1);   // reg loads fly during tile t's ds_reads + MFMA
    const char* pa = (const char*)&Al[t & 1][0] + wm * 8192 + lane * 16;
    const char* pb = (const char*)&Bl[t & 1][0] + lane * 16;
    bf16x8 av[4][2], bv[2][2];
#pragma unroll
    for (int f = 0; f < 4; ++f)
#pragma unroll
      for (int ks = 0; ks < 2; ++ks)
        av[f][ks] = *(const bf16x8*)(pa + (f * 2 + ks) * 1024);
#pragma unroll
    for (int fn = 0; fn < 2; ++fn)
#pragma unroll
      for (int ks = 0; ks < 2; ++ks) {
        const int r16 = wn * 2 + fn;
        bv[fn][ks] = *(const bf16x8*)(pb + ((r16 >> 2) * 8 + (r16 & 3) * 2 + ks) * 1024);
      }
    __builtin_amdgcn_s_setprio(1);
#pragma unroll
    for (int fm = 0; fm < 4; ++fm)
#pragma unroll
      for (int fn = 0; fn < 2; ++fn) {
        acc[fm][fn] = __builtin_amdgcn_mfma_f32_16x16x32_bf16(av[fm][0], bv[fn][0], acc[fm][fn], 0, 0, 0);
        acc[fm][fn] = __builtin_amdgcn_mfma_f32_16x16x32_bf16(av[fm][1], bv[fn][1], acc[fm][fn], 0, 0, 0);
      }
    __builtin_amdgcn_s_setprio(0);
    if (t + 1 < 4) MAwrite(t + 1);  // reg-dep waits its own loads; then ds_write
    asm volatile("s_waitcnt vmcnt(0) lgkmcnt(0)" ::: "memory");
    __builtin_amdgcn_s_barrier();
  }

#pragma unroll
  for (int fm = 0; fm < 4; ++fm)
#pragma unroll
    for (int fn = 0; fn < 2; ++fn) {
      const int r0 = m0 + wm * 64 + fm * 16 + g * 4;
      const int c = n0 + wn * 32 + fn * 16 + qi;
#pragma unroll
      for (int j = 0; j < 4; ++j) {
        const int r = r0 + j;
        outp[(size_t)r * 256 + c] = acc[fm][fn][j] + bias[c] + res[(size_t)r * 256 + c];
      }
    }
}

// ---------------- flash attention v5 (frozen: r7 version, ~92-94 us) -----------------------
__global__ __launch_bounds__(256) void attn_fwd(const bf16* __restrict__ qk,
                                                const bf16* __restrict__ vT,
                                                bf16* __restrict__ po0,
                                                bf16* __restrict__ po1,
                                                float* __restrict__ pstats) {
  __shared__ bf16 Kl[2][4096];
  __shared__ bf16 Vl[2][4096];
  __shared__ bf16 Pl[4][1024];
  const int tid = threadIdx.x;
  const int lane = tid & 63;
  const int w = tid >> 6;
  const int g = lane >> 4;
  const int qi = lane & 15;
  const int bid = (int)blockIdx.x;
  const int bh = bid & 31;
  const int qt = (bid >> 5) & 15;
  const int s = bid >> 9;
  const int b = bh >> 2, h = bh & 3;

  const size_t qrow0 = (size_t)b * 2048 + qt * 128 + w * 32 + qi;
  bf16x8 qf[2][2];
#pragma unroll
  for (int f = 0; f < 2; ++f) {
    const bf16* qp = qk + (qrow0 + f * 16) * 512 + h * 64 + g * 8;
    qf[f][0] = *(const bf16x8*)qp;
    qf[f][1] = *(const bf16x8*)(qp + 32);
  }

  float mrun[2] = {0.f, 0.f};
  float lsum[2] = {0.f, 0.f};
  f32x4 o[4][2];
#pragma unroll
  for (int i = 0; i < 4; ++i)
#pragma unroll
    for (int f = 0; f < 2; ++f) o[i][f] = (f32x4){0.f, 0.f, 0.f, 0.f};

  constexpr float THR = 8.0f / CEXP;

  const char* kbase = (const char*)qk + ((size_t)b * 2048) * 1024 + 512 + h * 128 +
                      (size_t)s * 16 * 65536;
  const char* vbase = (const char*)vT + (size_t)bh * 262144 + (size_t)s * 16 * 128;
  const char* ks[2];
  const char* vs[2];
#pragma unroll
  for (int i = 0; i < 2; ++i) {
    const int fk = i * 2 + (w >> 1);
    const int half = w & 1;
    ks[i] = kbase + (fk * 16 + qi) * 1024 + half * 64 + g * 16;
    vs[i] = vbase + (size_t)(fk * 16 + qi) * 4096 + half * 64 + g * 16;
  }
  char* const pw = (char*)&Pl[w][0];
  int paddrb[2];
#pragma unroll
  for (int bb = 0; bb < 2; ++bb)
    paddrb[bb] = (bb * 2 + (g >> 1)) * 256 + qi * 16 + (g & 1) * 8;
  const char* const prd = pw + lane * 16;

  auto stage = [&](int slot) {
    char* kd = (char*)&Kl[0][0] + slot * 8192 + w * 1024;
    char* vd = (char*)&Vl[0][0] + slot * 8192 + w * 1024;
    gload16(ks[0], kd);
    gload16(ks[1], kd + 4096);
    gload16(vs[0], vd);
    gload16(vs[1], vd + 4096);
    ks[0] += 65536; ks[1] += 65536;
    vs[0] += 128;   vs[1] += 128;
  };

  stage(0);
  asm volatile("s_waitcnt vmcnt(0)" ::: "memory");
  __builtin_amdgcn_s_barrier();

  for (int t = 0; t < 16; ++t) {
    if (t < 15) stage((t + 1) & 1);
    const char* kb = (const char*)&Kl[0][0] + (t & 1) * 8192 + lane * 16;
    f32x4 st[4][2];
    __builtin_amdgcn_s_setprio(1);
#pragma unroll
    for (int fk = 0; fk < 4; ++fk) {
      const bf16x8 k0 = *(const bf16x8*)(kb + fk * 2048);
      const bf16x8 k1 = *(const bf16x8*)(kb + fk * 2048 + 1024);
#pragma unroll
      for (int f = 0; f < 2; ++f) {
        f32x4 z = (f32x4){0.f, 0.f, 0.f, 0.f};
        st[fk][f] = __builtin_amdgcn_mfma_f32_16x16x32_bf16(k0, qf[f][0], z, 0, 0, 0);
        st[fk][f] = __builtin_amdgcn_mfma_f32_16x16x32_bf16(k1, qf[f][1], st[fk][f], 0, 0, 0);
      }
    }
    __builtin_amdgcn_s_setprio(0);
    float pmax[2];
#pragma unroll
    for (int f = 0; f < 2; ++f) {
      float m0 = fmaxf(fmaxf(st[0][f][0], st[0][f][1]), fmaxf(st[0][f][2], st[0][f][3]));
      float m1 = fmaxf(fmaxf(st[1][f][0], st[1][f][1]), fmaxf(st[1][f][2], st[1][f][3]));
      float m2 = fmaxf(fmaxf(st[2][f][0], st[2][f][1]), fmaxf(st[2][f][2], st[2][f][3]));
      float m3 = fmaxf(fmaxf(st[3][f][0], st[3][f][1]), fmaxf(st[3][f][2], st[3][f][3]));
      pmax[f] = fmaxf(fmaxf(m0, m1), fmaxf(m2, m3));
    }
    if (!__all(pmax[0] <= mrun[0] + THR && pmax[1] <= mrun[1] + THR)) {
#pragma unroll
      for (int f = 0; f < 2; ++f) {
        float mt = fmaxf(pmax[f], __shfl_xor(pmax[f], 16));
        mt = fmaxf(mt, __shfl_xor(mt, 32));
        const float mnew = fmaxf(mrun[f], mt);
        const float alpha = exp2f(CEXP * (mrun[f] - mnew));
        lsum[f] *= alpha;
#pragma unroll
        for (int fd = 0; fd < 4; ++fd)
#pragma unroll
          for (int j = 0; j < 4; ++j) o[fd][f][j] *= alpha;
        mrun[f] = mnew;
      }
    }
    unsigned pk[4][2][2];
#pragma unroll
    for (int f = 0; f < 2; ++f) {
      const float negcm = -CEXP * mrun[f];
      float ts = 0.f;
#pragma unroll
      for (int fk = 0; fk < 4; ++fk)
#pragma unroll
        for (int jp = 0; jp < 2; ++jp) {
          const float p0 = exp2f(fmaf(st[fk][f][2 * jp], CEXP, negcm));
          const float p1 = exp2f(fmaf(st[fk][f][2 * jp + 1], CEXP, negcm));
          ts += p0 + p1;
          union { bf16 h2[2]; unsigned u; } cv;
          cv.h2[0] = (bf16)p0;
          cv.h2[1] = (bf16)p1;
          pk[fk][f][jp] = cv.u;
        }
      lsum[f] += ts;
    }
    const char* vb = (const char*)&Vl[0][0] + (t & 1) * 8192 + lane * 16;
#pragma unroll
    for (int ksl = 0; ksl < 2; ++ksl) {
#pragma unroll
      for (int bb = 0; bb < 2; ++bb) {
        const int fk = 2 * ksl + bb;
#pragma unroll
        for (int f = 0; f < 2; ++f) {
          u32x2 pv2;
          pv2[0] = pk[fk][f][0];
          pv2[1] = pk[fk][f][1];
          *(u32x2*)(pw + f * 1024 + paddrb[bb]) = pv2;
        }
      }
      bf16x8 pa[2];
#pragma unroll
      for (int f = 0; f < 2; ++f) pa[f] = *(const bf16x8*)(prd + f * 1024);
      __builtin_amdgcn_s_setprio(1);
#pragma unroll
      for (int fd = 0; fd < 4; ++fd) {
        const bf16x8 vv = *(const bf16x8*)(vb + fd * 2048 + ksl * 1024);
#pragma unroll
        for (int f = 0; f < 2; ++f)
          o[fd][f] = __builtin_amdgcn_mfma_f32_16x16x32_bf16(vv, pa[f], o[fd][f], 0, 0, 0);
      }
      __builtin_amdgcn_s_setprio(0);
    }
    asm volatile("s_waitcnt vmcnt(0)" ::: "memory");
    __builtin_amdgcn_s_barrier();
  }

#pragma unroll
  for (int f = 0; f < 2; ++f) {
    float l = lsum[f];
    l += __shfl_xor(l, 16);
    l += __shfl_xor(l, 32);
    lsum[f] = l;
  }
  if (g == 0) {
#pragma unroll
    for (int f = 0; f < 2; ++f) {
      float2 sv;
      sv.x = mrun[f];
      sv.y = lsum[f];
      *(float2*)(pstats + (((size_t)s * 32 + bh) * 2048 + qt * 128 + w * 32 + f * 16 + qi) * 2) = sv;
    }
  }
  bf16* const pob = s ? po1 : po0;
#pragma unroll
  for (int f = 0; f < 2; ++f) {
    bf16* const orow = pob + (qrow0 + f * 16) * 256 + h * 64 + g * 4;
#pragma unroll
    for (int fd = 0; fd < 4; ++fd) {
      bf16x4 ov;
#pragma unroll
      for (int j = 0; j < 4; ++j) ov[j] = (bf16)o[fd][f][j];
      *(bf16x4*)(orow + fd * 16) = ov;
    }
  }
}

extern "C" void kernel_launch(void* const* d_in, const int* in_sizes, int n_in,
                              void* d_out, int out_size, void* d_ws, size_t ws_size,
                              hipStream_t stream) {
  const float* x      = (const float*)d_in[0];
  const float* qkv_w  = (const float*)d_in[1];
  const float* qkv_b  = (const float*)d_in[2];
  const float* proj_w = (const float*)d_in[3];
  const float* proj_b = (const float*)d_in[4];
  const float* ln1_g  = (const float*)d_in[5];
  const float* ln1_b  = (const float*)d_in[6];
  const float* ln2_g  = (const float*)d_in[7];
  const float* ln2_b  = (const float*)d_in[8];
  const float* mlp_w1 = (const float*)d_in[9];
  const float* mlp_b1 = (const float*)d_in[10];
  const float* mlp_w2 = (const float*)d_in[11];
  const float* mlp_b2 = (const float*)d_in[12];
  float* out = (float*)d_out;

  char* ws = (char*)d_ws;
  bf16* Wtqkv = (bf16*)(ws);              // [768][256]   393216 B
  bf16* WtP   = (bf16*)(ws + 393216);     // [256][256]   131072 B
  bf16* Wt1   = (bf16*)(ws + 524288);     // [512][256]   262144 B
  bf16* Wt2   = (bf16*)(ws + 786432);     // [256][512]   262144 B
  bf16* h     = (bf16*)(ws + 1048576);    // [16384][256] 8388608 B  (ln1 out; dead after V gemm)
  bf16* qkb   = (bf16*)(ws + 9437184);    // [16384][512] 16777216 B
  bf16* vT    = (bf16*)(ws + 26214400);   // [32][64][2048] 8388608 B
  bf16* po1   = (bf16*)(ws + 34603008);   // [16384][256] 8388608 B  (kv-half-1 partial)
  float* x2   = (float*)(ws + 42991616);  // [16384][256] 16777216 B
  float* pstats = (float*)(ws + 59768832);// [2][32][2048][2] f32  1 MB  (total 60.8 MB)
  bf16* po0 = h;   // kv-half-0 partial reuses h (dead once attn starts)
  bf16* a1 = qkb;  // fc1 out reuses qkb (dead after attn)
  bf16* h2 = h;    // ln2 out reuses h region (po0 dead after proj)

  // wconv (512 blocks) + ln1 (4096 blocks) fused
  prep_fused<<<4608, 256, 0, stream>>>(qkv_w, proj_w, mlp_w1, mlp_w2, Wtqkv, WtP, Wt1, Wt2,
                                       x, ln1_g, ln1_b, h);
  // QK gemm (512 blocks) + V^T gemm (256 blocks) in one launch
  gemm_qkv_fused<<<768, 512, 0, stream>>>(h, Wtqkv, qkv_b, qkb, vT);
  attn_fwd<<<1024, 256, 0, stream>>>(qkb, vT, po0, po1, pstats);
  // proj + residual -> x2 (f32), flash-merge fused into A-staging (no separate merge kernel)
  gemm_proj_merge<<<256, 512, 0, stream>>>(po0, po1, pstats, WtP, proj_b, x, x2);
  ln_fwd<<<4096, 256, 0, stream>>>(x2, ln2_g, ln2_b, h2);
  // fc1 + gelu -> a1 (bf16)
  gemm_one<3, 2><<<512, 512, 0, stream>>>(h2, Wt1, mlp_b1, nullptr, a1, 16384, 512, 256);
  // fc2 + residual -> out (f32)  [3-deep counted-vmcnt pipeline]
  gemm_one<2, 3><<<256, 512, 0, stream>>>(a1, Wt2, mlp_b2, x2, out, 16384, 256, 512);
}

// Round 12
// 158.560 us; speedup vs baseline: 1.4173x; 1.0123x over previous
//
#include <hip/hip_runtime.h>

typedef __bf16 bf16;
typedef __bf16 bf16x8 __attribute__((ext_vector_type(8)));
typedef __bf16 bf16x4 __attribute__((ext_vector_type(4)));
typedef float  f32x4  __attribute__((ext_vector_type(4)));
typedef unsigned u32x2 __attribute__((ext_vector_type(2)));

typedef __attribute__((address_space(1))) const void GASV;
typedef __attribute__((address_space(3))) void LASV;

__device__ __forceinline__ void gload16(const void* g, void* l) {
  __builtin_amdgcn_global_load_lds((GASV*)g, (LASV*)l, 16, 0, 0);
}

constexpr float CEXP = 0.125f * 1.44269504088896340736f;  // attn scale folded into exp2

// ---------------- fused: weight transposes (blocks 0-511) + layernorm1 (blocks 512-4607) ----
__global__ __launch_bounds__(256) void prep_fused(const float* __restrict__ qkv_w,
                                                  const float* __restrict__ proj_w,
                                                  const float* __restrict__ w1,
                                                  const float* __restrict__ w2,
                                                  bf16* __restrict__ Wtqkv,
                                                  bf16* __restrict__ WtP,
                                                  bf16* __restrict__ Wt1,
                                                  bf16* __restrict__ Wt2,
                                                  const float* __restrict__ x,
                                                  const float* __restrict__ gam,
                                                  const float* __restrict__ bet,
                                                  bf16* __restrict__ hout) {
  __shared__ float td[32][33];
  const int blk = blockIdx.x;
  const int tid = threadIdx.x;
  if (blk >= 512) {   // ---- layernorm path ----
    const int lane = tid & 63;
    const int w = tid >> 6;
    const size_t row = (size_t)(blk - 512) * 4 + w;
    const float4 v = *(const float4*)(x + row * 256 + lane * 4);
    float s1 = v.x + v.y + v.z + v.w;
    float s2 = v.x * v.x + v.y * v.y + v.z * v.z + v.w * v.w;
#pragma unroll
    for (int m = 1; m < 64; m <<= 1) {
      s1 += __shfl_xor(s1, m);
      s2 += __shfl_xor(s2, m);
    }
    const float mu = s1 * (1.0f / 256.0f);
    const float var = s2 * (1.0f / 256.0f) - mu * mu;
    const float rs = rsqrtf(var + 1e-5f);
    const float4 g4 = *(const float4*)(gam + lane * 4);
    const float4 b4 = *(const float4*)(bet + lane * 4);
    bf16x4 o;
    o[0] = (bf16)((v.x - mu) * rs * g4.x + b4.x);
    o[1] = (bf16)((v.y - mu) * rs * g4.y + b4.y);
    o[2] = (bf16)((v.z - mu) * rs * g4.z + b4.z);
    o[3] = (bf16)((v.w - mu) * rs * g4.w + b4.w);
    *(bf16x4*)(hout + row * 256 + lane * 4) = o;
    return;
  }
  // ---- weight transpose path ----
  const int t = blk;
  const float* src;
  bf16* dst;
  int Kin, Nin, kt, nt;
  if (t < 192)      { src = qkv_w; dst = Wtqkv; Kin = 256; Nin = 768; kt = t & 7;          nt = t >> 3; }
  else if (t < 256) { src = proj_w; dst = WtP;  Kin = 256; Nin = 256; kt = (t - 192) & 7;  nt = (t - 192) >> 3; }
  else if (t < 384) { src = w1;    dst = Wt1;   Kin = 256; Nin = 512; kt = (t - 256) & 7;  nt = (t - 256) >> 3; }
  else              { src = w2;    dst = Wt2;   Kin = 512; Nin = 256; kt = (t - 384) & 15; nt = (t - 384) >> 4; }
  {
    const int r = tid >> 3, c4 = (tid & 7) << 2;
    const float4 v = *(const float4*)(src + (size_t)(kt * 32 + r) * Nin + nt * 32 + c4);
    td[r][c4 + 0] = v.x; td[r][c4 + 1] = v.y; td[r][c4 + 2] = v.z; td[r][c4 + 3] = v.w;
  }
  __syncthreads();
  {
    const int n = tid >> 3, k4 = (tid & 7) << 2;
    bf16x4 o;
#pragma unroll
    for (int i = 0; i < 4; ++i) o[i] = (bf16)td[k4 + i][n];
    *(bf16x4*)(dst + (size_t)(nt * 32 + n) * Kin + kt * 32 + k4) = o;
  }
}

// ---------------- layernorm rows of 256 (fp32 in -> bf16 out); 1 wave per row ----------------
__global__ __launch_bounds__(256) void ln_fwd(const float* __restrict__ x,
                                              const float* __restrict__ gam,
                                              const float* __restrict__ bet,
                                              bf16* __restrict__ out) {
  const int lane = threadIdx.x & 63;
  const int w = threadIdx.x >> 6;
  const size_t row = (size_t)blockIdx.x * 4 + w;
  const float4 v = *(const float4*)(x + row * 256 + lane * 4);
  float s1 = v.x + v.y + v.z + v.w;
  float s2 = v.x * v.x + v.y * v.y + v.z * v.z + v.w * v.w;
#pragma unroll
  for (int m = 1; m < 64; m <<= 1) {
    s1 += __shfl_xor(s1, m);
    s2 += __shfl_xor(s2, m);
  }
  const float mu = s1 * (1.0f / 256.0f);
  const float var = s2 * (1.0f / 256.0f) - mu * mu;
  const float rs = rsqrtf(var + 1e-5f);
  const float4 g4 = *(const float4*)(gam + lane * 4);
  const float4 b4 = *(const float4*)(bet + lane * 4);
  bf16x4 o;
  o[0] = (bf16)((v.x - mu) * rs * g4.x + b4.x);
  o[1] = (bf16)((v.y - mu) * rs * g4.y + b4.y);
  o[2] = (bf16)((v.z - mu) * rs * g4.z + b4.z);
  o[3] = (bf16)((v.w - mu) * rs * g4.w + b4.w);
  *(bf16x4*)(out + row * 256 + lane * 4) = o;
}

// ---------------- BT-form GEMM core: 128x128 tile, BK=64, 512 thr (8 waves 2x4) ------------
template <int EPI, int NB>
__device__ __forceinline__ void gemm_core(bf16* __restrict__ ldsA, bf16* __restrict__ ldsB,
                                          const bf16* __restrict__ A,
                                          const bf16* __restrict__ Bt,
                                          const float* __restrict__ bias,
                                          const float* __restrict__ res,
                                          void* __restrict__ outp,
                                          int M, int N, int K, int bid) {
  const int tid = threadIdx.x;
  const int lane = tid & 63;
  const int W = tid >> 6;          // 0..7
  const int wm = W >> 2, wn = W & 3;
  const int qi = lane & 15, g = lane >> 4;
  const int nbm = M >> 7;
  const int bm = bid % nbm;
  const int bn = bid / nbm;
  const int m0 = bm << 7, n0 = bn << 7;
  const int nk = K >> 6;

  const char* asrc[2];
  const char* bsrc[2];
#pragma unroll
  for (int p = 0; p < 2; ++p) {
    const int s = p * 8 + W;
    const int row = (s >> 3) * 64 + ((s >> 1) & 3) * 16 + qi;
    const int kb = (s & 1) * 64 + g * 16;
    asrc[p] = (const char*)(A + (size_t)(m0 + row) * K) + kb;
    bsrc[p] = (const char*)(Bt + (size_t)(n0 + row) * K) + kb;
  }

  f32x4 acc[4][2];
#pragma unroll
  for (int i = 0; i < 4; ++i)
#pragma unroll
    for (int j = 0; j < 2; ++j) acc[i][j] = (f32x4){0.f, 0.f, 0.f, 0.f};

  auto stage = [&](int sl) {
#pragma unroll
    for (int p = 0; p < 2; ++p) {
      gload16(asrc[p], (char*)ldsA + sl * 16384 + (p * 8 + W) * 1024);
      gload16(bsrc[p], (char*)ldsB + sl * 16384 + (p * 8 + W) * 1024);
      asrc[p] += 128;
      bsrc[p] += 128;
    }
  };

  if constexpr (NB == 2) {
    stage(0);
    asm volatile("s_waitcnt vmcnt(0)" ::: "memory");
  } else {
    stage(0);
    stage(1);
    asm volatile("s_waitcnt vmcnt(4)" ::: "memory");   // tile0 done, tile1 in flight
  }
  __builtin_amdgcn_s_barrier();

  int cur = 0, nxt = (NB == 2) ? 1 : 2;
  for (int t = 0; t < nk; ++t) {
    if constexpr (NB == 2) {
      if (t + 1 < nk) stage(nxt);
    }
    const char* pa = (const char*)ldsA + cur * 16384 + wm * 8192 + lane * 16;
    const char* pb = (const char*)ldsB + cur * 16384 + lane * 16;
    bf16x8 av[4][2], bv[2][2];
#pragma unroll
    for (int f = 0; f < 4; ++f)
#pragma unroll
      for (int ks = 0; ks < 2; ++ks)
        av[f][ks] = *(const bf16x8*)(pa + (f * 2 + ks) * 1024);
#pragma unroll
    for (int fn = 0; fn < 2; ++fn)
#pragma unroll
      for (int ks = 0; ks < 2; ++ks) {
        const int r16 = wn * 2 + fn;
        bv[fn][ks] = *(const bf16x8*)(pb + ((r16 >> 2) * 8 + (r16 & 3) * 2 + ks) * 1024);
      }
    if constexpr (NB == 3) {
      if (t + 2 < nk) stage(nxt);   // issue 2-ahead; lands while tile t / t+1 compute
    }
    __builtin_amdgcn_s_setprio(1);
#pragma unroll
    for (int fm = 0; fm < 4; ++fm)
#pragma unroll
      for (int fn = 0; fn < 2; ++fn) {
        acc[fm][fn] = __builtin_amdgcn_mfma_f32_16x16x32_bf16(av[fm][0], bv[fn][0], acc[fm][fn], 0, 0, 0);
        acc[fm][fn] = __builtin_amdgcn_mfma_f32_16x16x32_bf16(av[fm][1], bv[fn][1], acc[fm][fn], 0, 0, 0);
      }
    __builtin_amdgcn_s_setprio(0);
    if constexpr (NB == 2) {
      asm volatile("s_waitcnt vmcnt(0)" ::: "memory");
    } else {
      if (t + 2 < nk) {
        asm volatile("s_waitcnt vmcnt(4)" ::: "memory");  // drain only tile t+1's loads
      } else {
        asm volatile("s_waitcnt vmcnt(0)" ::: "memory");  // tail
      }
    }
    __builtin_amdgcn_s_barrier();
    cur = (cur == NB - 1) ? 0 : cur + 1;
    nxt = (nxt == NB - 1) ? 0 : nxt + 1;
  }

#pragma unroll
  for (int fm = 0; fm < 4; ++fm)
#pragma unroll
    for (int fn = 0; fn < 2; ++fn) {
      const int r0 = m0 + wm * 64 + fm * 16 + g * 4;
      const int c = n0 + wn * 32 + fn * 16 + qi;
#pragma unroll
      for (int j = 0; j < 4; ++j) {
        const int r = r0 + j;
        const float v = acc[fm][fn][j];
        if constexpr (EPI == 0) {
          ((bf16*)outp)[(size_t)r * N + c] = (bf16)(v + bias[c]);
        } else if constexpr (EPI == 1) {
          ((bf16*)outp)[(size_t)r * 2048 + ((size_t)(c >> 11)) * 524288 + (c & 2047)] =
              (bf16)(v + bias[r]);
        } else if constexpr (EPI == 2) {
          ((float*)outp)[(size_t)r * N + c] = v + bias[c] + res[(size_t)r * N + c];
        } else {
          const float u = v + bias[c];
          ((bf16*)outp)[(size_t)r * N + c] = (bf16)(u * 0.5f * (1.0f + erff(u * 0.70710678118f)));
        }
      }
    }
}

// fused QK-gemm (blocks 0-511) + V-gemm (blocks 512-767), both NB=2 (shared 64KB LDS)
__global__ __launch_bounds__(512) void gemm_qkv_fused(const bf16* __restrict__ h,
                                                      const bf16* __restrict__ Wtqkv,
                                                      const float* __restrict__ qkv_b,
                                                      bf16* __restrict__ qkb,
                                                      bf16* __restrict__ vT) {
  __shared__ bf16 ldsA[2 * 8192];
  __shared__ bf16 ldsB[2 * 8192];
  const int bid = (int)blockIdx.x;
  if (bid < 512) {
    gemm_core<0, 2>(ldsA, ldsB, h, Wtqkv, qkv_b, nullptr, qkb, 16384, 512, 256, bid);
  } else {
    gemm_core<1, 2>(ldsA, ldsB, Wtqkv + 512 * 256, h, qkv_b + 512, nullptr, vT,
                    256, 16384, 256, bid - 512);
  }
}

template <int EPI, int NB>
__global__ __launch_bounds__(512) void gemm_one(const bf16* __restrict__ A,
                                                const bf16* __restrict__ Bt,
                                                const float* __restrict__ bias,
                                                const float* __restrict__ res,
                                                void* __restrict__ outp,
                                                int M, int N, int K) {
  __shared__ bf16 ldsA[NB * 8192];
  __shared__ bf16 ldsB[NB * 8192];
  gemm_core<EPI, NB>(ldsA, ldsB, A, Bt, bias, res, outp, M, N, K, (int)blockIdx.x);
}

// ---------------- proj GEMM with flash-merge fused into A-staging (unchanged r11) ----------
__global__ __launch_bounds__(512) void gemm_proj_merge(const bf16* __restrict__ po0,
                                                       const bf16* __restrict__ po1,
                                                       const float* __restrict__ pstats,
                                                       const bf16* __restrict__ Bt,
                                                       const float* __restrict__ bias,
                                                       const float* __restrict__ res,
                                                       float* __restrict__ outp) {
  __shared__ bf16 Al[2][8192];
  __shared__ bf16 Bl[2][8192];
  const int tid = threadIdx.x;
  const int lane = tid & 63;
  const int W = tid >> 6;
  const int wm = W >> 2, wn = W & 3;
  const int qi = lane & 15, g = lane >> 4;
  const int bm = (int)blockIdx.x & 127;   // nbm = 128 (M=16384)
  const int bn = (int)blockIdx.x >> 7;    // N=256 -> 2
  const int m0 = bm << 7, n0 = bn << 7;

  int rowg[2];
  const char* asrc[2];
  const char* bsrc[2];
#pragma unroll
  for (int p = 0; p < 2; ++p) {
    const int s = p * 8 + W;
    const int row = (s >> 3) * 64 + ((s >> 1) & 3) * 16 + qi;
    const int kb = (s & 1) * 64 + g * 16;
    rowg[p] = m0 + row;
    asrc[p] = (const char*)po0 + (size_t)(m0 + row) * 512 + kb;
    bsrc[p] = (const char*)(Bt + (size_t)(n0 + row) * 256) + kb;
  }
  const size_t dpo = (size_t)((const char*)po1 - (const char*)po0);

  f32x4 acc[4][2];
#pragma unroll
  for (int i = 0; i < 4; ++i)
#pragma unroll
    for (int j = 0; j < 2; ++j) acc[i][j] = (f32x4){0.f, 0.f, 0.f, 0.f};

  bf16x8 pa0v[2], pa1v[2];
  float2 sst0[2], sst1[2];

  auto MAload = [&](int t) {
#pragma unroll
    for (int p = 0; p < 2; ++p) {
      gload16(bsrc[p], (char*)&Bl[t & 1][0] + (p * 8 + W) * 1024);
      bsrc[p] += 128;
      pa0v[p] = *(const bf16x8*)(asrc[p]);
      pa1v[p] = *(const bf16x8*)(asrc[p] + dpo);
      asrc[p] += 128;
      const int bh = ((rowg[p] >> 11) << 2) + t;   // head == K-tile index
      const int ql = rowg[p] & 2047;
      sst0[p] = *(const float2*)(pstats + ((size_t)bh * 2048 + ql) * 2);
      sst1[p] = *(const float2*)(pstats + ((size_t)(bh + 32) * 2048 + ql) * 2);
    }
  };
  auto MAwrite = [&](int t) {
#pragma unroll
    for (int p = 0; p < 2; ++p) {
      const float mx = fmaxf(sst0[p].x, sst1[p].x);
      float a0 = exp2f(CEXP * (sst0[p].x - mx));
      float a1 = exp2f(CEXP * (sst1[p].x - mx));
      const float inv = 1.0f / (sst0[p].y * a0 + sst1[p].y * a1);
      a0 *= inv;
      a1 *= inv;
      bf16x8 wv;
#pragma unroll
      for (int j = 0; j < 8; ++j)
        wv[j] = (bf16)((float)pa0v[p][j] * a0 + (float)pa1v[p][j] * a1);
      *(bf16x8*)((char*)&Al[t & 1][0] + (p * 8 + W) * 1024 + lane * 16) = wv;
    }
  };

  MAload(0);
  MAwrite(0);
  asm volatile("s_waitcnt vmcnt(0) lgkmcnt(0)" ::: "memory");
  __builtin_amdgcn_s_barrier();

  for (int t = 0; t < 4; ++t) {
    if (t + 1 < 4) MAload(t + 1);   // reg loads fly during tile t's ds_reads + MFMA
    const char* pa = (const char*)&Al[t & 1][0] + wm * 8192 + lane * 16;
    const char* pb = (const char*)&Bl[t & 1][0] + lane * 16;
    bf16x8 av[4][2], bv[2][2];
#pragma unroll
    for (int f = 0; f < 4; ++f)
#pragma unroll
      for (int ks = 0; ks < 2; ++ks)
        av[f][ks] = *(const bf16x8*)(pa + (f * 2 + ks) * 1024);
#pragma unroll
    for (int fn = 0; fn < 2; ++fn)
#pragma unroll
      for (int ks = 0; ks < 2; ++ks) {
        const int r16 = wn * 2 + fn;
        bv[fn][ks] = *(const bf16x8*)(pb + ((r16 >> 2) * 8 + (r16 & 3) * 2 + ks) * 1024);
      }
    __builtin_amdgcn_s_setprio(1);
#pragma unroll
    for (int fm = 0; fm < 4; ++fm)
#pragma unroll
      for (int fn = 0; fn < 2; ++fn) {
        acc[fm][fn] = __builtin_amdgcn_mfma_f32_16x16x32_bf16(av[fm][0], bv[fn][0], acc[fm][fn], 0, 0, 0);
        acc[fm][fn] = __builtin_amdgcn_mfma_f32_16x16x32_bf16(av[fm][1], bv[fn][1], acc[fm][fn], 0, 0, 0);
      }
    __builtin_amdgcn_s_setprio(0);
    if (t + 1 < 4) MAwrite(t + 1);  // reg-dep waits its own loads; then ds_write
    asm volatile("s_waitcnt vmcnt(0) lgkmcnt(0)" ::: "memory");
    __builtin_amdgcn_s_barrier();
  }

#pragma unroll
  for (int fm = 0; fm < 4; ++fm)
#pragma unroll
    for (int fn = 0; fn < 2; ++fn) {
      const int r0 = m0 + wm * 64 + fm * 16 + g * 4;
      const int c = n0 + wn * 32 + fn * 16 + qi;
#pragma unroll
      for (int j = 0; j < 4; ++j) {
        const int r = r0 + j;
        outp[(size_t)r * 256 + c] = acc[fm][fn][j] + bias[c] + res[(size_t)r * 256 + c];
      }
    }
}

// ---------------- flash attention v7: K 3-slot / V 2-slot, counted vmcnt(2) ----------------
// Same structure as frozen v5 except: K prefetch 2 iterations ahead (3 LDS slots), V one
// ahead (2 slots); end-of-iter wait is vmcnt(2) (K(t+2)'s 2 loads stay in flight across the
// barrier) instead of a full vmcnt(0) drain. LDS 48KB -> 3 blocks/CU.
__global__ __launch_bounds__(256) void attn_fwd(const bf16* __restrict__ qk,
                                                const bf16* __restrict__ vT,
                                                bf16* __restrict__ po0,
                                                bf16* __restrict__ po1,
                                                float* __restrict__ pstats) {
  __shared__ bf16 Kl[3][4096];
  __shared__ bf16 Vl[2][4096];
  __shared__ bf16 Pl[4][1024];
  const int tid = threadIdx.x;
  const int lane = tid & 63;
  const int w = tid >> 6;
  const int g = lane >> 4;
  const int qi = lane & 15;
  const int bid = (int)blockIdx.x;
  const int bh = bid & 31;
  const int qt = (bid >> 5) & 15;
  const int s = bid >> 9;
  const int b = bh >> 2, h = bh & 3;

  const size_t qrow0 = (size_t)b * 2048 + qt * 128 + w * 32 + qi;
  bf16x8 qf[2][2];
#pragma unroll
  for (int f = 0; f < 2; ++f) {
    const bf16* qp = qk + (qrow0 + f * 16) * 512 + h * 64 + g * 8;
    qf[f][0] = *(const bf16x8*)qp;
    qf[f][1] = *(const bf16x8*)(qp + 32);
  }

  float mrun[2] = {0.f, 0.f};
  float lsum[2] = {0.f, 0.f};
  f32x4 o[4][2];
#pragma unroll
  for (int i = 0; i < 4; ++i)
#pragma unroll
    for (int f = 0; f < 2; ++f) o[i][f] = (f32x4){0.f, 0.f, 0.f, 0.f};

  constexpr float THR = 8.0f / CEXP;

  const char* kbase = (const char*)qk + ((size_t)b * 2048) * 1024 + 512 + h * 128 +
                      (size_t)s * 16 * 65536;
  const char* vbase = (const char*)vT + (size_t)bh * 262144 + (size_t)s * 16 * 128;
  const char* ks[2];
  const char* vs[2];
#pragma unroll
  for (int i = 0; i < 2; ++i) {
    const int fk = i * 2 + (w >> 1);
    const int half = w & 1;
    ks[i] = kbase + (fk * 16 + qi) * 1024 + half * 64 + g * 16;
    vs[i] = vbase + (size_t)(fk * 16 + qi) * 4096 + half * 64 + g * 16;
  }
  char* const pw = (char*)&Pl[w][0];
  int paddrb[2];
#pragma unroll
  for (int bb = 0; bb < 2; ++bb)
    paddrb[bb] = (bb * 2 + (g >> 1)) * 256 + qi * 16 + (g & 1) * 8;
  const char* const prd = pw + lane * 16;

  auto stageK = [&](int slot) {
    char* kd = (char*)&Kl[0][0] + slot * 8192 + w * 1024;
    gload16(ks[0], kd);
    gload16(ks[1], kd + 4096);
    ks[0] += 65536; ks[1] += 65536;
  };
  auto stageV = [&](int slot) {
    char* vd = (char*)&Vl[0][0] + slot * 8192 + w * 1024;
    gload16(vs[0], vd);
    gload16(vs[1], vd + 4096);
    vs[0] += 128; vs[1] += 128;
  };

  // prologue: K0, V0 ready; K1 in flight
  stageK(0);
  stageV(0);
  stageK(1);
  asm volatile("s_waitcnt vmcnt(2)" ::: "memory");
  __builtin_amdgcn_s_barrier();

  int kslot = 0, k2 = 2;
  for (int t = 0; t < 16; ++t) {
    // issue V(t+1) then K(t+2); both land while this + next iteration compute
    if (t < 15) stageV((t + 1) & 1);
    if (t < 14) stageK(k2);
    const char* kb = (const char*)&Kl[0][0] + kslot * 8192 + lane * 16;
    f32x4 st[4][2];
    __builtin_amdgcn_s_setprio(1);
#pragma unroll
    for (int fk = 0; fk < 4; ++fk) {
      const bf16x8 k0 = *(const bf16x8*)(kb + fk * 2048);
      const bf16x8 k1 = *(const bf16x8*)(kb + fk * 2048 + 1024);
#pragma unroll
      for (int f = 0; f < 2; ++f) {
        f32x4 z = (f32x4){0.f, 0.f, 0.f, 0.f};
        st[fk][f] = __builtin_amdgcn_mfma_f32_16x16x32_bf16(k0, qf[f][0], z, 0, 0, 0);
        st[fk][f] = __builtin_amdgcn_mfma_f32_16x16x32_bf16(k1, qf[f][1], st[fk][f], 0, 0, 0);
      }
    }
    __builtin_amdgcn_s_setprio(0);
    float pmax[2];
#pragma unroll
    for (int f = 0; f < 2; ++f) {
      float m0 = fmaxf(fmaxf(st[0][f][0], st[0][f][1]), fmaxf(st[0][f][2], st[0][f][3]));
      float m1 = fmaxf(fmaxf(st[1][f][0], st[1][f][1]), fmaxf(st[1][f][2], st[1][f][3]));
      float m2 = fmaxf(fmaxf(st[2][f][0], st[2][f][1]), fmaxf(st[2][f][2], st[2][f][3]));
      float m3 = fmaxf(fmaxf(st[3][f][0], st[3][f][1]), fmaxf(st[3][f][2], st[3][f][3]));
      pmax[f] = fmaxf(fmaxf(m0, m1), fmaxf(m2, m3));
    }
    if (!__all(pmax[0] <= mrun[0] + THR && pmax[1] <= mrun[1] + THR)) {
#pragma unroll
      for (int f = 0; f < 2; ++f) {
        float mt = fmaxf(pmax[f], __shfl_xor(pmax[f], 16));
        mt = fmaxf(mt, __shfl_xor(mt, 32));
        const float mnew = fmaxf(mrun[f], mt);
        const float alpha = exp2f(CEXP * (mrun[f] - mnew));
        lsum[f] *= alpha;
#pragma unroll
        for (int fd = 0; fd < 4; ++fd)
#pragma unroll
          for (int j = 0; j < 4; ++j) o[fd][f][j] *= alpha;
        mrun[f] = mnew;
      }
    }
    unsigned pk[4][2][2];
#pragma unroll
    for (int f = 0; f < 2; ++f) {
      const float negcm = -CEXP * mrun[f];
      float ts = 0.f;
#pragma unroll
      for (int fk = 0; fk < 4; ++fk)
#pragma unroll
        for (int jp = 0; jp < 2; ++jp) {
          const float p0 = exp2f(fmaf(st[fk][f][2 * jp], CEXP, negcm));
          const float p1 = exp2f(fmaf(st[fk][f][2 * jp + 1], CEXP, negcm));
          ts += p0 + p1;
          union { bf16 h2[2]; unsigned u; } cv;
          cv.h2[0] = (bf16)p0;
          cv.h2[1] = (bf16)p1;
          pk[fk][f][jp] = cv.u;
        }
      lsum[f] += ts;
    }
    const char* vb = (const char*)&Vl[0][0] + (t & 1) * 8192 + lane * 16;
#pragma unroll
    for (int ksl = 0; ksl < 2; ++ksl) {
#pragma unroll
      for (int bb = 0; bb < 2; ++bb) {
        const int fk = 2 * ksl + bb;
#pragma unroll
        for (int f = 0; f < 2; ++f) {
          u32x2 pv2;
          pv2[0] = pk[fk][f][0];
          pv2[1] = pk[fk][f][1];
          *(u32x2*)(pw + f * 1024 + paddrb[bb]) = pv2;
        }
      }
      bf16x8 pa[2];
#pragma unroll
      for (int f = 0; f < 2; ++f) pa[f] = *(const bf16x8*)(prd + f * 1024);
      __builtin_amdgcn_s_setprio(1);
#pragma unroll
      for (int fd = 0; fd < 4; ++fd) {
        const bf16x8 vv = *(const bf16x8*)(vb + fd * 2048 + ksl * 1024);
#pragma unroll
        for (int f = 0; f < 2; ++f)
          o[fd][f] = __builtin_amdgcn_mfma_f32_16x16x32_bf16(vv, pa[f], o[fd][f], 0, 0, 0);
      }
      __builtin_amdgcn_s_setprio(0);
    }
    // counted wait: K(t+1)/V(t+1) must be resident; K(t+2)'s 2 loads stay in flight
    if (t < 14) {
      asm volatile("s_waitcnt vmcnt(2)" ::: "memory");
    } else {
      asm volatile("s_waitcnt vmcnt(0)" ::: "memory");
    }
    __builtin_amdgcn_s_barrier();
    kslot = (kslot == 2) ? 0 : kslot + 1;
    k2 = (k2 == 2) ? 0 : k2 + 1;
  }

#pragma unroll
  for (int f = 0; f < 2; ++f) {
    float l = lsum[f];
    l += __shfl_xor(l, 16);
    l += __shfl_xor(l, 32);
    lsum[f] = l;
  }
  if (g == 0) {
#pragma unroll
    for (int f = 0; f < 2; ++f) {
      float2 sv;
      sv.x = mrun[f];
      sv.y = lsum[f];
      *(float2*)(pstats + (((size_t)s * 32 + bh) * 2048 + qt * 128 + w * 32 + f * 16 + qi) * 2) = sv;
    }
  }
  bf16* const pob = s ? po1 : po0;
#pragma unroll
  for (int f = 0; f < 2; ++f) {
    bf16* const orow = pob + (qrow0 + f * 16) * 256 + h * 64 + g * 4;
#pragma unroll
    for (int fd = 0; fd < 4; ++fd) {
      bf16x4 ov;
#pragma unroll
      for (int j = 0; j < 4; ++j) ov[j] = (bf16)o[fd][f][j];
      *(bf16x4*)(orow + fd * 16) = ov;
    }
  }
}

extern "C" void kernel_launch(void* const* d_in, const int* in_sizes, int n_in,
                              void* d_out, int out_size, void* d_ws, size_t ws_size,
                              hipStream_t stream) {
  const float* x      = (const float*)d_in[0];
  const float* qkv_w  = (const float*)d_in[1];
  const float* qkv_b  = (const float*)d_in[2];
  const float* proj_w = (const float*)d_in[3];
  const float* proj_b = (const float*)d_in[4];
  const float* ln1_g  = (const float*)d_in[5];
  const float* ln1_b  = (const float*)d_in[6];
  const float* ln2_g  = (const float*)d_in[7];
  const float* ln2_b  = (const float*)d_in[8];
  const float* mlp_w1 = (const float*)d_in[9];
  const float* mlp_b1 = (const float*)d_in[10];
  const float* mlp_w2 = (const float*)d_in[11];
  const float* mlp_b2 = (const float*)d_in[12];
  float* out = (float*)d_out;

  char* ws = (char*)d_ws;
  bf16* Wtqkv = (bf16*)(ws);              // [768][256]   393216 B
  bf16* WtP   = (bf16*)(ws + 393216);     // [256][256]   131072 B
  bf16* Wt1   = (bf16*)(ws + 524288);     // [512][256]   262144 B
  bf16* Wt2   = (bf16*)(ws + 786432);     // [256][512]   262144 B
  bf16* h     = (bf16*)(ws + 1048576);    // [16384][256] 8388608 B  (ln1 out; dead after V gemm)
  bf16* qkb   = (bf16*)(ws + 9437184);    // [16384][512] 16777216 B
  bf16* vT    = (bf16*)(ws + 26214400);   // [32][64][2048] 8388608 B
  bf16* po1   = (bf16*)(ws + 34603008);   // [16384][256] 8388608 B  (kv-half-1 partial)
  float* x2   = (float*)(ws + 42991616);  // [16384][256] 16777216 B
  float* pstats = (float*)(ws + 59768832);// [2][32][2048][2] f32  1 MB  (total 60.8 MB)
  bf16* po0 = h;   // kv-half-0 partial reuses h (dead once attn starts)
  bf16* a1 = qkb;  // fc1 out reuses qkb (dead after attn)
  bf16* h2 = h;    // ln2 out reuses h region (po0 dead after proj)

  // wconv (512 blocks) + ln1 (4096 blocks) fused
  prep_fused<<<4608, 256, 0, stream>>>(qkv_w, proj_w, mlp_w1, mlp_w2, Wtqkv, WtP, Wt1, Wt2,
                                       x, ln1_g, ln1_b, h);
  // QK gemm (512 blocks) + V^T gemm (256 blocks) in one launch
  gemm_qkv_fused<<<768, 512, 0, stream>>>(h, Wtqkv, qkv_b, qkb, vT);
  attn_fwd<<<1024, 256, 0, stream>>>(qkb, vT, po0, po1, pstats);
  // proj + residual -> x2 (f32), flash-merge fused into A-staging
  gemm_proj_merge<<<256, 512, 0, stream>>>(po0, po1, pstats, WtP, proj_b, x, x2);
  ln_fwd<<<4096, 256, 0, stream>>>(x2, ln2_g, ln2_b, h2);
  // fc1 + gelu -> a1 (bf16)
  gemm_one<3, 2><<<512, 512, 0, stream>>>(h2, Wt1, mlp_b1, nullptr, a1, 16384, 512, 256);
  // fc2 + residual -> out (f32)  [3-deep counted-vmcnt pipeline]
  gemm_one<2, 3><<<256, 512, 0, stream>>>(a1, Wt2, mlp_b2, x2, out, 16384, 256, 512);
}